// Round 15
// baseline (247.677 us; speedup 1.0000x reference)
//
#include <hip/hip_runtime.h>
#include <hip/hip_bf16.h>

typedef __attribute__((ext_vector_type(8))) short bf16x8;
typedef __attribute__((ext_vector_type(4))) short bf16x4;
typedef __attribute__((ext_vector_type(4))) float f32x4;

#define LDS_PAD 72
#define LOG2E 1.44269504088896f

static __device__ __forceinline__ float bf2f(__hip_bfloat16 v) { return __bfloat162float(v); }

// load 8 consecutive f32, round to bf16x8
static __device__ __forceinline__ bf16x8 ld8f_bf16(const float* __restrict__ p) {
    const float4 a = *(const float4*)p;
    const float4 b = *(const float4*)(p + 4);
    bf16x8 r;
    __hip_bfloat16* h = (__hip_bfloat16*)&r;
    h[0] = __float2bfloat16(a.x); h[1] = __float2bfloat16(a.y);
    h[2] = __float2bfloat16(a.z); h[3] = __float2bfloat16(a.w);
    h[4] = __float2bfloat16(b.x); h[5] = __float2bfloat16(b.y);
    h[6] = __float2bfloat16(b.z); h[7] = __float2bfloat16(b.w);
    return r;
}

// async global->LDS, 16B per lane; lds base must be wave-uniform
static __device__ __forceinline__ void gload_lds16(const __hip_bfloat16* g, __hip_bfloat16* l) {
    __builtin_amdgcn_global_load_lds(
        (const __attribute__((address_space(1))) void*)g,
        (__attribute__((address_space(3))) void*)l, 16, 0, 0);
}

// ---------------------------------------------------------------------------
// Kernel 0a/0b: f32 -> bf16 conversion (x, and the 4 weight matrices).
// ---------------------------------------------------------------------------
__global__ __launch_bounds__(256) void cvt_x(const float* __restrict__ src,
                                             __hip_bfloat16* __restrict__ dst) {
    const int i = (blockIdx.x * 256 + threadIdx.x) * 8;
    *(bf16x8*)(dst + i) = ld8f_bf16(src + i);
}

__global__ __launch_bounds__(256) void cvt_w(const float* __restrict__ w0,
                                             const float* __restrict__ w1,
                                             const float* __restrict__ w2,
                                             const float* __restrict__ w3,
                                             __hip_bfloat16* __restrict__ dst) {
    const float* srcs[4] = {w0, w1, w2, w3};
    const int b = blockIdx.y;
    const int i = (blockIdx.x * 256 + threadIdx.x) * 8;
    *(bf16x8*)(dst + (size_t)b * 589824 + i) = ld8f_bf16(srcs[b] + i);
}

// ---------------------------------------------------------------------------
// Kernel 1: fused QKV projection, 512 threads / 8 waves (wave tile 32x64).
// 2-PHASE double-buffered gload_lds schedule (T3-min): one barrier per
// K-step; next tile's loads issued BEFORE the MFMA phase; vmcnt(0) placed
// AFTER the MFMAs so load latency hides under compute.
// Outputs:
//   qr, kr : [((b*12+nh)*1024 + l)*64 + d]   (q pre-scaled by log2e)
//   v_t    : [((b*12+nh)*64 + d)*1024 + l]
// ---------------------------------------------------------------------------
__global__ __launch_bounds__(512) void qkv_gemm(
    const __hip_bfloat16* __restrict__ xb,
    const __hip_bfloat16* __restrict__ wb,
    const float* __restrict__ bq, const float* __restrict__ bk,
    const float* __restrict__ bv,
    const float* __restrict__ sinp, const float* __restrict__ cosp,
    __hip_bfloat16* __restrict__ qr, __hip_bfloat16* __restrict__ kr,
    __hip_bfloat16* __restrict__ v_t)
{
    __shared__ __align__(16) __hip_bfloat16 Alds[2][128 * 64];
    __shared__ __align__(16) __hip_bfloat16 Blds[2][128 * 64];

    const int t    = threadIdx.x;
    const int lane = t & 63;
    const int w    = t >> 6;           // 0..7
    const int wm   = w >> 1, wn = w & 1;
    const int l15  = lane & 15, lhi = lane >> 4;

    const int rm   = blockIdx.x;       // row tile 0..63
    const int cy   = blockIdx.y;       // 0..17
    const int wsel = cy / 6;           // 0=q,1=k,2=v
    const int cn   = cy % 6;

    const __hip_bfloat16* wgt = wb + (size_t)wsel * 589824;
    const float* bias = (wsel == 0) ? bq : (wsel == 1) ? bk : bv;

    const int srow = w * 16 + (lane >> 3);
    const int scol = (lane & 7) * 8;
    const __hip_bfloat16* asrc = xb  + (size_t)(rm * 128 + srow) * 768 + scol;
    const __hip_bfloat16* bsrc = wgt + (size_t)(cn * 128 + srow) * 768 + scol;

    f32x4 acc[2][4] = {};

    // prologue: stage K-tile 0 into buffer 0, drain, barrier
    #pragma unroll
    for (int j = 0; j < 2; ++j) {
        gload_lds16(asrc + (size_t)j * 8 * 768, Alds[0] + (w * 2 + j) * 512);
        gload_lds16(bsrc + (size_t)j * 8 * 768, Blds[0] + (w * 2 + j) * 512);
    }
    asm volatile("s_waitcnt vmcnt(0)" ::: "memory");
    __syncthreads();

    int cur = 0;
    for (int k0 = 0; k0 < 768; k0 += 64) {
        // issue next tile's async loads into the spare buffer (in flight
        // during this iteration's MFMA phase)
        if (k0 + 64 < 768) {
            #pragma unroll
            for (int j = 0; j < 2; ++j) {
                gload_lds16(asrc + (size_t)j * 8 * 768 + k0 + 64, Alds[cur ^ 1] + (w * 2 + j) * 512);
                gload_lds16(bsrc + (size_t)j * 8 * 768 + k0 + 64, Blds[cur ^ 1] + (w * 2 + j) * 512);
            }
        }
        // compute from current buffer
        #pragma unroll
        for (int kk = 0; kk < 2; ++kk) {
            bf16x8 af[2], bfr[4];
            #pragma unroll
            for (int m = 0; m < 2; ++m)
                af[m] = *(const bf16x8*)&Alds[cur][(wm * 32 + m * 16 + l15) * 64 + kk * 32 + lhi * 8];
            #pragma unroll
            for (int n = 0; n < 4; ++n)
                bfr[n] = *(const bf16x8*)&Blds[cur][(wn * 64 + n * 16 + l15) * 64 + kk * 32 + lhi * 8];
            #pragma unroll
            for (int m = 0; m < 2; ++m)
                #pragma unroll
                for (int n = 0; n < 4; ++n)
                    acc[m][n] = __builtin_amdgcn_mfma_f32_16x16x32_bf16(af[m], bfr[n], acc[m][n], 0, 0, 0);
        }
        // wait for next tile's loads (issued pre-compute -> mostly landed)
        asm volatile("s_waitcnt vmcnt(0)" ::: "memory");
        __syncthreads();
        cur ^= 1;
    }

    // Epilogue: bias, RoPE (q,k), scaling (k: 0.125, q: log2e), scatter.
    #pragma unroll
    for (int m = 0; m < 2; ++m) {
        #pragma unroll
        for (int n = 0; n < 4; ++n) {
            const int gcol = cn * 128 + wn * 64 + n * 16 + l15;   // 0..767
            const float bcol = bias[gcol];
            const int nh = gcol >> 6, d = gcol & 63;
            const int grow0 = rm * 128 + wm * 32 + m * 16 + lhi * 4;
            const int bb = grow0 >> 10, ll0 = grow0 & 1023;
            if (wsel == 2) {
                bf16x4 pk;
                #pragma unroll
                for (int r = 0; r < 4; ++r)
                    ((__hip_bfloat16*)&pk)[r] = __float2bfloat16(acc[m][n][r] + bcol);
                *(bf16x4*)&v_t[(size_t)((bb * 12 + nh) * 64 + d) * 1024 + ll0] = pk;
            } else {
                #pragma unroll
                for (int r = 0; r < 4; ++r) {
                    const int ll = ll0 + r;
                    const float val = acc[m][n][r] + bcol;
                    const float other = __shfl_xor(val, 1);
                    const float cs = cosp[ll * 64 + d];
                    const float sn = sinp[ll * 64 + d];
                    float res = val * cs + ((d & 1) ? other : -other) * sn;
                    res *= (wsel == 1) ? 0.125f : LOG2E;
                    __hip_bfloat16* dst = (wsel == 1) ? kr : qr;
                    dst[(size_t)((bb * 12 + nh) * 1024 + ll) * 64 + d] = __float2bfloat16(res);
                }
            }
        }
    }
}

// ---------------------------------------------------------------------------
// Kernel 2: flash-style attention (r14 best-known: swapped-operand, LDS-staged
// K/V + register prefetch, static exp2 softmax, mask prefetched one kt ahead).
// ---------------------------------------------------------------------------
__global__ __launch_bounds__(256) void attn_kernel(
    const __hip_bfloat16* __restrict__ qr,
    const __hip_bfloat16* __restrict__ kr,
    const __hip_bfloat16* __restrict__ v_t,
    const float* __restrict__ mask,
    __hip_bfloat16* __restrict__ attn_out)
{
    __shared__ __align__(16) __hip_bfloat16 Klds[64][LDS_PAD];
    __shared__ __align__(16) __hip_bfloat16 Vtlds[64][LDS_PAD];
    __shared__ __align__(16) __hip_bfloat16 Pq[4][16][LDS_PAD];

    const int qt = blockIdx.x;      // 0..15
    const int bh = blockIdx.y;      // 0..95
    const int b = bh / 12, nh = bh % 12;

    const int t = threadIdx.x, lane = t & 63, w = t >> 6;
    const int l15 = lane & 15, lhi = lane >> 4;
    const int qg = qt * 64 + w * 16 + l15;

    bf16x8 qf[2];   // q pre-scaled by log2(e)
    qf[0] = *(const bf16x8*)&qr[((size_t)bh * 1024 + qg) * 64 + lhi * 8];
    qf[1] = *(const bf16x8*)&qr[((size_t)bh * 1024 + qg) * 64 + 32 + lhi * 8];

    f32x4 o[4] = {};
    float l_run = 0.f;

    const int srow = t >> 3;
    const int scol = (t & 7) * 8;

    const float* mbase = mask + ((size_t)nh << 20) + (size_t)qg * 1024;

    bf16x8 kb0, kb1, vb0, vb1;
    float4 mv[4];
    {
        const size_t kbase = ((size_t)bh * 1024) * 64;
        kb0 = *(const bf16x8*)&kr[kbase + (size_t)srow * 64 + scol];
        kb1 = *(const bf16x8*)&kr[kbase + (size_t)(srow + 32) * 64 + scol];
        const size_t vbase = (size_t)bh * 64 * 1024;
        vb0 = *(const bf16x8*)&v_t[vbase + (size_t)srow * 1024 + scol];
        vb1 = *(const bf16x8*)&v_t[vbase + (size_t)(srow + 32) * 1024 + scol];
        #pragma unroll
        for (int n = 0; n < 4; ++n)
            mv[n] = *(const float4*)&mbase[n * 16 + lhi * 4];
    }

    for (int kt = 0; kt < 16; ++kt) {
        *(bf16x8*)&Klds[srow][scol]       = kb0;
        *(bf16x8*)&Klds[srow + 32][scol]  = kb1;
        *(bf16x8*)&Vtlds[srow][scol]      = vb0;
        *(bf16x8*)&Vtlds[srow + 32][scol] = vb1;
        __syncthreads();

        float4 mvn[4];
        if (kt < 15) {
            const size_t kbase = ((size_t)bh * 1024 + (kt + 1) * 64) * 64;
            kb0 = *(const bf16x8*)&kr[kbase + (size_t)srow * 64 + scol];
            kb1 = *(const bf16x8*)&kr[kbase + (size_t)(srow + 32) * 64 + scol];
            const size_t vbase = (size_t)bh * 64 * 1024 + (kt + 1) * 64;
            vb0 = *(const bf16x8*)&v_t[vbase + (size_t)srow * 1024 + scol];
            vb1 = *(const bf16x8*)&v_t[vbase + (size_t)(srow + 32) * 1024 + scol];
            #pragma unroll
            for (int n = 0; n < 4; ++n)
                mvn[n] = *(const float4*)&mbase[(kt + 1) * 64 + n * 16 + lhi * 4];
        }

        f32x4 s[4] = {};
        __builtin_amdgcn_s_setprio(1);
        #pragma unroll
        for (int n = 0; n < 4; ++n) {
            const bf16x8 kf0 = *(const bf16x8*)&Klds[n * 16 + l15][lhi * 8];
            const bf16x8 kf1 = *(const bf16x8*)&Klds[n * 16 + l15][32 + lhi * 8];
            s[n] = __builtin_amdgcn_mfma_f32_16x16x32_bf16(kf0, qf[0], s[n], 0, 0, 0);
            s[n] = __builtin_amdgcn_mfma_f32_16x16x32_bf16(kf1, qf[1], s[n], 0, 0, 0);
        }
        __builtin_amdgcn_s_setprio(0);

        #pragma unroll
        for (int n = 0; n < 4; ++n) {
            bf16x4 pk;
            #pragma unroll
            for (int r = 0; r < 4; ++r) {
                const float p = exp2f(fmaf(((const float*)&mv[n])[r], LOG2E, s[n][r]));
                l_run += p;
                ((__hip_bfloat16*)&pk)[r] = __float2bfloat16(p);
            }
            *(bf16x4*)&Pq[w][l15][n * 16 + lhi * 4] = pk;
        }
        asm volatile("s_waitcnt lgkmcnt(0)" ::: "memory");
        __builtin_amdgcn_sched_barrier(0);

        __builtin_amdgcn_s_setprio(1);
        #pragma unroll
        for (int ks = 0; ks < 2; ++ks) {
            const bf16x8 pf = *(const bf16x8*)&Pq[w][l15][ks * 32 + lhi * 8];
            #pragma unroll
            for (int m = 0; m < 4; ++m) {
                const bf16x8 vf = *(const bf16x8*)&Vtlds[m * 16 + l15][ks * 32 + lhi * 8];
                o[m] = __builtin_amdgcn_mfma_f32_16x16x32_bf16(vf, pf, o[m], 0, 0, 0);
            }
        }
        __builtin_amdgcn_s_setprio(0);
        __syncthreads();

        #pragma unroll
        for (int n = 0; n < 4; ++n) mv[n] = mvn[n];
    }

    l_run += __shfl_xor(l_run, 16);
    l_run += __shfl_xor(l_run, 32);

    const float rl = 1.f / l_run;
    #pragma unroll
    for (int m = 0; m < 4; ++m) {
        bf16x4 pk;
        #pragma unroll
        for (int r = 0; r < 4; ++r)
            ((__hip_bfloat16*)&pk)[r] = __float2bfloat16(o[m][r] * rl);
        *(bf16x4*)&attn_out[((size_t)b * 1024 + qg) * 768 + nh * 64 + m * 16 + lhi * 4] = pk;
    }
}

// ---------------------------------------------------------------------------
// Kernel 3: depthwise 5x5 conv (LEPE), fused add into aout (in-place).
// ---------------------------------------------------------------------------
__global__ __launch_bounds__(256) void lepe_conv(
    const __hip_bfloat16* __restrict__ v_t,
    const float* __restrict__ lw,
    const float* __restrict__ lb,
    __hip_bfloat16* __restrict__ aout)
{
    __shared__ __hip_bfloat16 img[8][1024];

    const int b  = blockIdx.x / 96;
    const int cg = blockIdx.x % 96;
    const int c0 = cg * 8;
    const int t  = threadIdx.x;

    for (int i = t; i < 2048; i += 256) {
        const int ci = i >> 8, l4 = (i & 255) << 2;
        const int c = c0 + ci, nh = c >> 6, d = c & 63;
        *(bf16x4*)&img[ci][l4] =
            *(const bf16x4*)&v_t[(size_t)((b * 12 + nh) * 64 + d) * 1024 + l4];
    }
    __syncthreads();

    const int ci = t & 7, c = c0 + ci;
    float wt[25];
    #pragma unroll
    for (int k = 0; k < 25; ++k) wt[k] = lw[k * 768 + c];
    const float bias = lb[c];

    for (int l0 = t >> 3; l0 < 1024; l0 += 32) {
        const int h = l0 >> 5, w = l0 & 31;
        float s = bias;
        #pragma unroll
        for (int dy = 0; dy < 5; ++dy) {
            const int hy = h + dy - 2;
            if (hy < 0 || hy > 31) continue;
            #pragma unroll
            for (int dx = 0; dx < 5; ++dx) {
                const int wx = w + dx - 2;
                if (wx < 0 || wx > 31) continue;
                s += bf2f(img[ci][hy * 32 + wx]) * wt[dy * 5 + dx];
            }
        }
        const size_t idx = (size_t)(b * 1024 + l0) * 768 + c;
        aout[idx] = __float2bfloat16(s + bf2f(aout[idx]));
    }
}

// ---------------------------------------------------------------------------
// Kernel 4: output projection, 512 threads / 8 waves, 2-phase double-buffered
// gload_lds schedule (same as qkv). out = aout @ wo^T + bo  (bf16 in, f32 out)
// ---------------------------------------------------------------------------
__global__ __launch_bounds__(512) void proj_gemm(
    const __hip_bfloat16* __restrict__ aout,
    const __hip_bfloat16* __restrict__ wb,
    const float* __restrict__ bo,
    float* __restrict__ out)
{
    __shared__ __align__(16) __hip_bfloat16 Alds[2][128 * 64];
    __shared__ __align__(16) __hip_bfloat16 Blds[2][128 * 64];

    const int t    = threadIdx.x;
    const int lane = t & 63;
    const int w    = t >> 6;
    const int wm   = w >> 1, wn = w & 1;
    const int l15  = lane & 15, lhi = lane >> 4;

    const int rm = blockIdx.x, cn = blockIdx.y;
    const __hip_bfloat16* wgt = wb + (size_t)3 * 589824;

    const int srow = w * 16 + (lane >> 3);
    const int scol = (lane & 7) * 8;
    const __hip_bfloat16* asrc = aout + (size_t)(rm * 128 + srow) * 768 + scol;
    const __hip_bfloat16* bsrc = wgt  + (size_t)(cn * 128 + srow) * 768 + scol;

    f32x4 acc[2][4] = {};

    #pragma unroll
    for (int j = 0; j < 2; ++j) {
        gload_lds16(asrc + (size_t)j * 8 * 768, Alds[0] + (w * 2 + j) * 512);
        gload_lds16(bsrc + (size_t)j * 8 * 768, Blds[0] + (w * 2 + j) * 512);
    }
    asm volatile("s_waitcnt vmcnt(0)" ::: "memory");
    __syncthreads();

    int cur = 0;
    for (int k0 = 0; k0 < 768; k0 += 64) {
        if (k0 + 64 < 768) {
            #pragma unroll
            for (int j = 0; j < 2; ++j) {
                gload_lds16(asrc + (size_t)j * 8 * 768 + k0 + 64, Alds[cur ^ 1] + (w * 2 + j) * 512);
                gload_lds16(bsrc + (size_t)j * 8 * 768 + k0 + 64, Blds[cur ^ 1] + (w * 2 + j) * 512);
            }
        }
        #pragma unroll
        for (int kk = 0; kk < 2; ++kk) {
            bf16x8 af[2], bfr[4];
            #pragma unroll
            for (int m = 0; m < 2; ++m)
                af[m] = *(const bf16x8*)&Alds[cur][(wm * 32 + m * 16 + l15) * 64 + kk * 32 + lhi * 8];
            #pragma unroll
            for (int n = 0; n < 4; ++n)
                bfr[n] = *(const bf16x8*)&Blds[cur][(wn * 64 + n * 16 + l15) * 64 + kk * 32 + lhi * 8];
            #pragma unroll
            for (int m = 0; m < 2; ++m)
                #pragma unroll
                for (int n = 0; n < 4; ++n)
                    acc[m][n] = __builtin_amdgcn_mfma_f32_16x16x32_bf16(af[m], bfr[n], acc[m][n], 0, 0, 0);
        }
        asm volatile("s_waitcnt vmcnt(0)" ::: "memory");
        __syncthreads();
        cur ^= 1;
    }

    #pragma unroll
    for (int m = 0; m < 2; ++m)
        #pragma unroll
        for (int n = 0; n < 4; ++n) {
            const int gcol = cn * 128 + wn * 64 + n * 16 + l15;
            const float bcol = bo[gcol];
            #pragma unroll
            for (int r = 0; r < 4; ++r) {
                const int grow = rm * 128 + wm * 32 + m * 16 + lhi * 4 + r;
                out[(size_t)grow * 768 + gcol] = acc[m][n][r] + bcol;
            }
        }
}

// ---------------------------------------------------------------------------
extern "C" void kernel_launch(void* const* d_in, const int* in_sizes, int n_in,
                              void* d_out, int out_size, void* d_ws, size_t ws_size,
                              hipStream_t stream) {
    const float* x    = (const float*)d_in[0];
    const float* sinp = (const float*)d_in[1];
    const float* cosp = (const float*)d_in[2];
    const float* mask = (const float*)d_in[3];
    const float* wq   = (const float*)d_in[4];
    const float* bq   = (const float*)d_in[5];
    const float* wk   = (const float*)d_in[6];
    const float* bk   = (const float*)d_in[7];
    const float* wvw  = (const float*)d_in[8];
    const float* bv   = (const float*)d_in[9];
    const float* lw   = (const float*)d_in[10];
    const float* lb   = (const float*)d_in[11];
    const float* wo   = (const float*)d_in[12];
    const float* bo   = (const float*)d_in[13];
    float* out = (float*)d_out;

    char* ws = (char*)d_ws;
    const size_t SZ = (size_t)8192 * 768 * 2;    // 12.58 MB per bf16 buffer
    __hip_bfloat16* qr   = (__hip_bfloat16*)(ws);
    __hip_bfloat16* kr   = (__hip_bfloat16*)(ws + SZ);
    __hip_bfloat16* v_t  = (__hip_bfloat16*)(ws + 2 * SZ);
    __hip_bfloat16* xb   = (__hip_bfloat16*)(ws + 3 * SZ);
    __hip_bfloat16* wb   = (__hip_bfloat16*)(ws + 4 * SZ);   // 4x768x768 bf16
    __hip_bfloat16* aout = xb;   // xb dead after qkv_gemm

    cvt_x<<<dim3(3072), 256, 0, stream>>>(x, xb);
    cvt_w<<<dim3(288, 4), 256, 0, stream>>>(wq, wk, wvw, wo, wb);
    qkv_gemm<<<dim3(64, 18), 512, 0, stream>>>(xb, wb, bq, bk, bv,
                                               sinp, cosp, qr, kr, v_t);
    attn_kernel<<<dim3(16, 96), 256, 0, stream>>>(qr, kr, v_t, mask, aout);
    lepe_conv<<<dim3(768), 256, 0, stream>>>(v_t, lw, lb, aout);
    proj_gemm<<<dim3(64, 6), 512, 0, stream>>>(aout, wb, bo, out);
}

// Round 16
// 240.154 us; speedup vs baseline: 1.0313x; 1.0313x over previous
//
#include <hip/hip_runtime.h>
#include <hip/hip_bf16.h>

typedef __attribute__((ext_vector_type(8))) short bf16x8;
typedef __attribute__((ext_vector_type(4))) short bf16x4;
typedef __attribute__((ext_vector_type(4))) float f32x4;

#define LDS_PAD 72
#define LOG2E 1.44269504088896f

static __device__ __forceinline__ float bf2f(__hip_bfloat16 v) { return __bfloat162float(v); }

// load 8 consecutive f32, round to bf16x8
static __device__ __forceinline__ bf16x8 ld8f_bf16(const float* __restrict__ p) {
    const float4 a = *(const float4*)p;
    const float4 b = *(const float4*)(p + 4);
    bf16x8 r;
    __hip_bfloat16* h = (__hip_bfloat16*)&r;
    h[0] = __float2bfloat16(a.x); h[1] = __float2bfloat16(a.y);
    h[2] = __float2bfloat16(a.z); h[3] = __float2bfloat16(a.w);
    h[4] = __float2bfloat16(b.x); h[5] = __float2bfloat16(b.y);
    h[6] = __float2bfloat16(b.z); h[7] = __float2bfloat16(b.w);
    return r;
}

// async global->LDS, 16B per lane; lds base must be wave-uniform
static __device__ __forceinline__ void gload_lds16(const __hip_bfloat16* g, __hip_bfloat16* l) {
    __builtin_amdgcn_global_load_lds(
        (const __attribute__((address_space(1))) void*)g,
        (__attribute__((address_space(3))) void*)l, 16, 0, 0);
}

// ---------------------------------------------------------------------------
// Kernel 0a/0b: f32 -> bf16 conversion (x, and the 4 weight matrices).
// ---------------------------------------------------------------------------
__global__ __launch_bounds__(256) void cvt_x(const float* __restrict__ src,
                                             __hip_bfloat16* __restrict__ dst) {
    const int i = (blockIdx.x * 256 + threadIdx.x) * 8;
    *(bf16x8*)(dst + i) = ld8f_bf16(src + i);
}

__global__ __launch_bounds__(256) void cvt_w(const float* __restrict__ w0,
                                             const float* __restrict__ w1,
                                             const float* __restrict__ w2,
                                             const float* __restrict__ w3,
                                             __hip_bfloat16* __restrict__ dst) {
    const float* srcs[4] = {w0, w1, w2, w3};
    const int b = blockIdx.y;
    const int i = (blockIdx.x * 256 + threadIdx.x) * 8;
    *(bf16x8*)(dst + (size_t)b * 589824 + i) = ld8f_bf16(srcs[b] + i);
}

// ---------------------------------------------------------------------------
// Kernel 1: fused QKV projection, 512 threads / 8 waves (wave tile 32x64).
// 2-phase double-buffered gload_lds, BK=32: LDS stays 32 KB (4 blocks/CU,
// occupancy-neutral vs 1-phase) while next tile's loads are in flight
// during every compute phase. 24 K-steps of 8 MFMAs each.
// Outputs:
//   qr, kr : [((b*12+nh)*1024 + l)*64 + d]   (q pre-scaled by log2e)
//   v_t    : [((b*12+nh)*64 + d)*1024 + l]
// ---------------------------------------------------------------------------
__global__ __launch_bounds__(512) void qkv_gemm(
    const __hip_bfloat16* __restrict__ xb,
    const __hip_bfloat16* __restrict__ wb,
    const float* __restrict__ bq, const float* __restrict__ bk,
    const float* __restrict__ bv,
    const float* __restrict__ sinp, const float* __restrict__ cosp,
    __hip_bfloat16* __restrict__ qr, __hip_bfloat16* __restrict__ kr,
    __hip_bfloat16* __restrict__ v_t)
{
    __shared__ __align__(16) __hip_bfloat16 Alds[2][128 * 32];   // 8 KB each
    __shared__ __align__(16) __hip_bfloat16 Blds[2][128 * 32];

    const int t    = threadIdx.x;
    const int lane = t & 63;
    const int w    = t >> 6;           // 0..7
    const int wm   = w >> 1, wn = w & 1;
    const int l15  = lane & 15, lhi = lane >> 4;

    const int rm   = blockIdx.x;       // row tile 0..63
    const int cy   = blockIdx.y;       // 0..17
    const int wsel = cy / 6;           // 0=q,1=k,2=v
    const int cn   = cy % 6;

    const __hip_bfloat16* wgt = wb + (size_t)wsel * 589824;
    const float* bias = (wsel == 0) ? bq : (wsel == 1) ? bk : bv;

    // staging: one 16B chunk per thread per matrix per K-step
    const int srow = w * 16 + (lane >> 2);   // 0..127
    const int scol = (lane & 3) * 8;         // 0..24
    const __hip_bfloat16* asrc = xb  + (size_t)(rm * 128 + srow) * 768 + scol;
    const __hip_bfloat16* bsrc = wgt + (size_t)(cn * 128 + srow) * 768 + scol;

    f32x4 acc[2][4] = {};

    // prologue: stage K-tile 0 into buffer 0, drain, barrier
    gload_lds16(asrc, Alds[0] + w * 512);
    gload_lds16(bsrc, Blds[0] + w * 512);
    asm volatile("s_waitcnt vmcnt(0)" ::: "memory");
    __syncthreads();

    int cur = 0;
    for (int k0 = 0; k0 < 768; k0 += 32) {
        // issue next tile's loads into the spare buffer (in flight during MFMA)
        if (k0 + 32 < 768) {
            gload_lds16(asrc + k0 + 32, Alds[cur ^ 1] + w * 512);
            gload_lds16(bsrc + k0 + 32, Blds[cur ^ 1] + w * 512);
        }
        // compute from current buffer (one K=32 step)
        {
            bf16x8 af[2], bfr[4];
            #pragma unroll
            for (int m = 0; m < 2; ++m)
                af[m] = *(const bf16x8*)&Alds[cur][(wm * 32 + m * 16 + l15) * 32 + lhi * 8];
            #pragma unroll
            for (int n = 0; n < 4; ++n)
                bfr[n] = *(const bf16x8*)&Blds[cur][(wn * 64 + n * 16 + l15) * 32 + lhi * 8];
            #pragma unroll
            for (int m = 0; m < 2; ++m)
                #pragma unroll
                for (int n = 0; n < 4; ++n)
                    acc[m][n] = __builtin_amdgcn_mfma_f32_16x16x32_bf16(af[m], bfr[n], acc[m][n], 0, 0, 0);
        }
        asm volatile("s_waitcnt vmcnt(0)" ::: "memory");
        __syncthreads();
        cur ^= 1;
    }

    // Epilogue: bias, RoPE (q,k), scaling (k: 0.125, q: log2e), scatter.
    #pragma unroll
    for (int m = 0; m < 2; ++m) {
        #pragma unroll
        for (int n = 0; n < 4; ++n) {
            const int gcol = cn * 128 + wn * 64 + n * 16 + l15;   // 0..767
            const float bcol = bias[gcol];
            const int nh = gcol >> 6, d = gcol & 63;
            const int grow0 = rm * 128 + wm * 32 + m * 16 + lhi * 4;
            const int bb = grow0 >> 10, ll0 = grow0 & 1023;
            if (wsel == 2) {
                bf16x4 pk;
                #pragma unroll
                for (int r = 0; r < 4; ++r)
                    ((__hip_bfloat16*)&pk)[r] = __float2bfloat16(acc[m][n][r] + bcol);
                *(bf16x4*)&v_t[(size_t)((bb * 12 + nh) * 64 + d) * 1024 + ll0] = pk;
            } else {
                #pragma unroll
                for (int r = 0; r < 4; ++r) {
                    const int ll = ll0 + r;
                    const float val = acc[m][n][r] + bcol;
                    const float other = __shfl_xor(val, 1);
                    const float cs = cosp[ll * 64 + d];
                    const float sn = sinp[ll * 64 + d];
                    float res = val * cs + ((d & 1) ? other : -other) * sn;
                    res *= (wsel == 1) ? 0.125f : LOG2E;
                    __hip_bfloat16* dst = (wsel == 1) ? kr : qr;
                    dst[(size_t)((bb * 12 + nh) * 1024 + ll) * 64 + d] = __float2bfloat16(res);
                }
            }
        }
    }
}

// ---------------------------------------------------------------------------
// Kernel 2: flash-style attention (r14 best-known: swapped-operand, LDS-staged
// K/V + register prefetch, static exp2 softmax, mask prefetched one kt ahead).
// ---------------------------------------------------------------------------
__global__ __launch_bounds__(256) void attn_kernel(
    const __hip_bfloat16* __restrict__ qr,
    const __hip_bfloat16* __restrict__ kr,
    const __hip_bfloat16* __restrict__ v_t,
    const float* __restrict__ mask,
    __hip_bfloat16* __restrict__ attn_out)
{
    __shared__ __align__(16) __hip_bfloat16 Klds[64][LDS_PAD];
    __shared__ __align__(16) __hip_bfloat16 Vtlds[64][LDS_PAD];
    __shared__ __align__(16) __hip_bfloat16 Pq[4][16][LDS_PAD];

    const int qt = blockIdx.x;      // 0..15
    const int bh = blockIdx.y;      // 0..95
    const int b = bh / 12, nh = bh % 12;

    const int t = threadIdx.x, lane = t & 63, w = t >> 6;
    const int l15 = lane & 15, lhi = lane >> 4;
    const int qg = qt * 64 + w * 16 + l15;

    bf16x8 qf[2];   // q pre-scaled by log2(e)
    qf[0] = *(const bf16x8*)&qr[((size_t)bh * 1024 + qg) * 64 + lhi * 8];
    qf[1] = *(const bf16x8*)&qr[((size_t)bh * 1024 + qg) * 64 + 32 + lhi * 8];

    f32x4 o[4] = {};
    float l_run = 0.f;

    const int srow = t >> 3;
    const int scol = (t & 7) * 8;

    const float* mbase = mask + ((size_t)nh << 20) + (size_t)qg * 1024;

    bf16x8 kb0, kb1, vb0, vb1;
    float4 mv[4];
    {
        const size_t kbase = ((size_t)bh * 1024) * 64;
        kb0 = *(const bf16x8*)&kr[kbase + (size_t)srow * 64 + scol];
        kb1 = *(const bf16x8*)&kr[kbase + (size_t)(srow + 32) * 64 + scol];
        const size_t vbase = (size_t)bh * 64 * 1024;
        vb0 = *(const bf16x8*)&v_t[vbase + (size_t)srow * 1024 + scol];
        vb1 = *(const bf16x8*)&v_t[vbase + (size_t)(srow + 32) * 1024 + scol];
        #pragma unroll
        for (int n = 0; n < 4; ++n)
            mv[n] = *(const float4*)&mbase[n * 16 + lhi * 4];
    }

    for (int kt = 0; kt < 16; ++kt) {
        *(bf16x8*)&Klds[srow][scol]       = kb0;
        *(bf16x8*)&Klds[srow + 32][scol]  = kb1;
        *(bf16x8*)&Vtlds[srow][scol]      = vb0;
        *(bf16x8*)&Vtlds[srow + 32][scol] = vb1;
        __syncthreads();

        float4 mvn[4];
        if (kt < 15) {
            const size_t kbase = ((size_t)bh * 1024 + (kt + 1) * 64) * 64;
            kb0 = *(const bf16x8*)&kr[kbase + (size_t)srow * 64 + scol];
            kb1 = *(const bf16x8*)&kr[kbase + (size_t)(srow + 32) * 64 + scol];
            const size_t vbase = (size_t)bh * 64 * 1024 + (kt + 1) * 64;
            vb0 = *(const bf16x8*)&v_t[vbase + (size_t)srow * 1024 + scol];
            vb1 = *(const bf16x8*)&v_t[vbase + (size_t)(srow + 32) * 1024 + scol];
            #pragma unroll
            for (int n = 0; n < 4; ++n)
                mvn[n] = *(const float4*)&mbase[(kt + 1) * 64 + n * 16 + lhi * 4];
        }

        f32x4 s[4] = {};
        __builtin_amdgcn_s_setprio(1);
        #pragma unroll
        for (int n = 0; n < 4; ++n) {
            const bf16x8 kf0 = *(const bf16x8*)&Klds[n * 16 + l15][lhi * 8];
            const bf16x8 kf1 = *(const bf16x8*)&Klds[n * 16 + l15][32 + lhi * 8];
            s[n] = __builtin_amdgcn_mfma_f32_16x16x32_bf16(kf0, qf[0], s[n], 0, 0, 0);
            s[n] = __builtin_amdgcn_mfma_f32_16x16x32_bf16(kf1, qf[1], s[n], 0, 0, 0);
        }
        __builtin_amdgcn_s_setprio(0);

        #pragma unroll
        for (int n = 0; n < 4; ++n) {
            bf16x4 pk;
            #pragma unroll
            for (int r = 0; r < 4; ++r) {
                const float p = exp2f(fmaf(((const float*)&mv[n])[r], LOG2E, s[n][r]));
                l_run += p;
                ((__hip_bfloat16*)&pk)[r] = __float2bfloat16(p);
            }
            *(bf16x4*)&Pq[w][l15][n * 16 + lhi * 4] = pk;
        }
        asm volatile("s_waitcnt lgkmcnt(0)" ::: "memory");
        __builtin_amdgcn_sched_barrier(0);

        __builtin_amdgcn_s_setprio(1);
        #pragma unroll
        for (int ks = 0; ks < 2; ++ks) {
            const bf16x8 pf = *(const bf16x8*)&Pq[w][l15][ks * 32 + lhi * 8];
            #pragma unroll
            for (int m = 0; m < 4; ++m) {
                const bf16x8 vf = *(const bf16x8*)&Vtlds[m * 16 + l15][ks * 32 + lhi * 8];
                o[m] = __builtin_amdgcn_mfma_f32_16x16x32_bf16(vf, pf, o[m], 0, 0, 0);
            }
        }
        __builtin_amdgcn_s_setprio(0);
        __syncthreads();

        #pragma unroll
        for (int n = 0; n < 4; ++n) mv[n] = mvn[n];
    }

    l_run += __shfl_xor(l_run, 16);
    l_run += __shfl_xor(l_run, 32);

    const float rl = 1.f / l_run;
    #pragma unroll
    for (int m = 0; m < 4; ++m) {
        bf16x4 pk;
        #pragma unroll
        for (int r = 0; r < 4; ++r)
            ((__hip_bfloat16*)&pk)[r] = __float2bfloat16(o[m][r] * rl);
        *(bf16x4*)&attn_out[((size_t)b * 1024 + qg) * 768 + nh * 64 + m * 16 + lhi * 4] = pk;
    }
}

// ---------------------------------------------------------------------------
// Kernel 3: depthwise 5x5 conv (LEPE), fused add into aout (in-place).
// ---------------------------------------------------------------------------
__global__ __launch_bounds__(256) void lepe_conv(
    const __hip_bfloat16* __restrict__ v_t,
    const float* __restrict__ lw,
    const float* __restrict__ lb,
    __hip_bfloat16* __restrict__ aout)
{
    __shared__ __hip_bfloat16 img[8][1024];

    const int b  = blockIdx.x / 96;
    const int cg = blockIdx.x % 96;
    const int c0 = cg * 8;
    const int t  = threadIdx.x;

    for (int i = t; i < 2048; i += 256) {
        const int ci = i >> 8, l4 = (i & 255) << 2;
        const int c = c0 + ci, nh = c >> 6, d = c & 63;
        *(bf16x4*)&img[ci][l4] =
            *(const bf16x4*)&v_t[(size_t)((b * 12 + nh) * 64 + d) * 1024 + l4];
    }
    __syncthreads();

    const int ci = t & 7, c = c0 + ci;
    float wt[25];
    #pragma unroll
    for (int k = 0; k < 25; ++k) wt[k] = lw[k * 768 + c];
    const float bias = lb[c];

    for (int l0 = t >> 3; l0 < 1024; l0 += 32) {
        const int h = l0 >> 5, w = l0 & 31;
        float s = bias;
        #pragma unroll
        for (int dy = 0; dy < 5; ++dy) {
            const int hy = h + dy - 2;
            if (hy < 0 || hy > 31) continue;
            #pragma unroll
            for (int dx = 0; dx < 5; ++dx) {
                const int wx = w + dx - 2;
                if (wx < 0 || wx > 31) continue;
                s += bf2f(img[ci][hy * 32 + wx]) * wt[dy * 5 + dx];
            }
        }
        const size_t idx = (size_t)(b * 1024 + l0) * 768 + c;
        aout[idx] = __float2bfloat16(s + bf2f(aout[idx]));
    }
}

// ---------------------------------------------------------------------------
// Kernel 4: output projection (512 threads / 8 waves, wave tile 32x64,
// 1-phase gload_lds staging — r14 known-good).
// out = aout @ wo^T + bo  (bf16 in, f32 out)
// ---------------------------------------------------------------------------
__global__ __launch_bounds__(512) void proj_gemm(
    const __hip_bfloat16* __restrict__ aout,
    const __hip_bfloat16* __restrict__ wb,
    const float* __restrict__ bo,
    float* __restrict__ out)
{
    __shared__ __align__(16) __hip_bfloat16 Alds[128 * 64];
    __shared__ __align__(16) __hip_bfloat16 Blds[128 * 64];

    const int t    = threadIdx.x;
    const int lane = t & 63;
    const int w    = t >> 6;
    const int wm   = w >> 1, wn = w & 1;
    const int l15  = lane & 15, lhi = lane >> 4;

    const int rm = blockIdx.x, cn = blockIdx.y;
    const __hip_bfloat16* wgt = wb + (size_t)3 * 589824;

    const int srow = w * 16 + (lane >> 3);
    const int scol = (lane & 7) * 8;
    const __hip_bfloat16* asrc = aout + (size_t)(rm * 128 + srow) * 768 + scol;
    const __hip_bfloat16* bsrc = wgt  + (size_t)(cn * 128 + srow) * 768 + scol;

    f32x4 acc[2][4] = {};

    for (int k0 = 0; k0 < 768; k0 += 64) {
        __syncthreads();
        #pragma unroll
        for (int j = 0; j < 2; ++j) {
            gload_lds16(asrc + (size_t)j * 8 * 768 + k0, Alds + (w * 2 + j) * 512);
            gload_lds16(bsrc + (size_t)j * 8 * 768 + k0, Blds + (w * 2 + j) * 512);
        }
        __syncthreads();
        #pragma unroll
        for (int kk = 0; kk < 2; ++kk) {
            bf16x8 af[2], bfr[4];
            #pragma unroll
            for (int m = 0; m < 2; ++m)
                af[m] = *(const bf16x8*)&Alds[(wm * 32 + m * 16 + l15) * 64 + kk * 32 + lhi * 8];
            #pragma unroll
            for (int n = 0; n < 4; ++n)
                bfr[n] = *(const bf16x8*)&Blds[(wn * 64 + n * 16 + l15) * 64 + kk * 32 + lhi * 8];
            #pragma unroll
            for (int m = 0; m < 2; ++m)
                #pragma unroll
                for (int n = 0; n < 4; ++n)
                    acc[m][n] = __builtin_amdgcn_mfma_f32_16x16x32_bf16(af[m], bfr[n], acc[m][n], 0, 0, 0);
        }
    }

    #pragma unroll
    for (int m = 0; m < 2; ++m)
        #pragma unroll
        for (int n = 0; n < 4; ++n) {
            const int gcol = cn * 128 + wn * 64 + n * 16 + l15;
            const float bcol = bo[gcol];
            #pragma unroll
            for (int r = 0; r < 4; ++r) {
                const int grow = rm * 128 + wm * 32 + m * 16 + lhi * 4 + r;
                out[(size_t)grow * 768 + gcol] = acc[m][n][r] + bcol;
            }
        }
}

// ---------------------------------------------------------------------------
extern "C" void kernel_launch(void* const* d_in, const int* in_sizes, int n_in,
                              void* d_out, int out_size, void* d_ws, size_t ws_size,
                              hipStream_t stream) {
    const float* x    = (const float*)d_in[0];
    const float* sinp = (const float*)d_in[1];
    const float* cosp = (const float*)d_in[2];
    const float* mask = (const float*)d_in[3];
    const float* wq   = (const float*)d_in[4];
    const float* bq   = (const float*)d_in[5];
    const float* wk   = (const float*)d_in[6];
    const float* bk   = (const float*)d_in[7];
    const float* wvw  = (const float*)d_in[8];
    const float* bv   = (const float*)d_in[9];
    const float* lw   = (const float*)d_in[10];
    const float* lb   = (const float*)d_in[11];
    const float* wo   = (const float*)d_in[12];
    const float* bo   = (const float*)d_in[13];
    float* out = (float*)d_out;

    char* ws = (char*)d_ws;
    const size_t SZ = (size_t)8192 * 768 * 2;    // 12.58 MB per bf16 buffer
    __hip_bfloat16* qr   = (__hip_bfloat16*)(ws);
    __hip_bfloat16* kr   = (__hip_bfloat16*)(ws + SZ);
    __hip_bfloat16* v_t  = (__hip_bfloat16*)(ws + 2 * SZ);
    __hip_bfloat16* xb   = (__hip_bfloat16*)(ws + 3 * SZ);
    __hip_bfloat16* wb   = (__hip_bfloat16*)(ws + 4 * SZ);   // 4x768x768 bf16
    __hip_bfloat16* aout = xb;   // xb dead after qkv_gemm

    cvt_x<<<dim3(3072), 256, 0, stream>>>(x, xb);
    cvt_w<<<dim3(288, 4), 256, 0, stream>>>(wq, wk, wvw, wo, wb);
    qkv_gemm<<<dim3(64, 18), 512, 0, stream>>>(xb, wb, bq, bk, bv,
                                               sinp, cosp, qr, kr, v_t);
    attn_kernel<<<dim3(16, 96), 256, 0, stream>>>(qr, kr, v_t, mask, aout);
    lepe_conv<<<dim3(768), 256, 0, stream>>>(v_t, lw, lb, aout);
    proj_gemm<<<dim3(64, 6), 512, 0, stream>>>(aout, wb, bo, out);
}

// Round 17
// 237.941 us; speedup vs baseline: 1.0409x; 1.0093x over previous
//
#include <hip/hip_runtime.h>
#include <hip/hip_bf16.h>

typedef __attribute__((ext_vector_type(8))) short bf16x8;
typedef __attribute__((ext_vector_type(4))) short bf16x4;
typedef __attribute__((ext_vector_type(4))) float f32x4;

#define LDS_PAD 72
#define LOG2E 1.44269504088896f

static __device__ __forceinline__ float bf2f(__hip_bfloat16 v) { return __bfloat162float(v); }

// load 8 consecutive f32, round to bf16x8
static __device__ __forceinline__ bf16x8 ld8f_bf16(const float* __restrict__ p) {
    const float4 a = *(const float4*)p;
    const float4 b = *(const float4*)(p + 4);
    bf16x8 r;
    __hip_bfloat16* h = (__hip_bfloat16*)&r;
    h[0] = __float2bfloat16(a.x); h[1] = __float2bfloat16(a.y);
    h[2] = __float2bfloat16(a.z); h[3] = __float2bfloat16(a.w);
    h[4] = __float2bfloat16(b.x); h[5] = __float2bfloat16(b.y);
    h[6] = __float2bfloat16(b.z); h[7] = __float2bfloat16(b.w);
    return r;
}

// async global->LDS, 16B per lane; lds base must be wave-uniform
static __device__ __forceinline__ void gload_lds16(const __hip_bfloat16* g, __hip_bfloat16* l) {
    __builtin_amdgcn_global_load_lds(
        (const __attribute__((address_space(1))) void*)g,
        (__attribute__((address_space(3))) void*)l, 16, 0, 0);
}

// ---------------------------------------------------------------------------
// Kernel 0: merged f32 -> bf16 conversion (x + the 4 weight matrices).
// blocks 0..3071: x (8192x768). blocks 3072..4223: weights (4 x 768x768).
// ---------------------------------------------------------------------------
__global__ __launch_bounds__(256) void cvt_in(
    const float* __restrict__ x,
    const float* __restrict__ w0, const float* __restrict__ w1,
    const float* __restrict__ w2, const float* __restrict__ w3,
    __hip_bfloat16* __restrict__ xb, __hip_bfloat16* __restrict__ wb)
{
    const int blk = blockIdx.x;
    if (blk < 3072) {
        const int i = (blk * 256 + threadIdx.x) * 8;
        *(bf16x8*)(xb + i) = ld8f_bf16(x + i);
    } else {
        const float* srcs[4] = {w0, w1, w2, w3};
        const int wblk = blk - 3072;
        const int b = wblk / 288;
        const int i = ((wblk % 288) * 256 + threadIdx.x) * 8;
        *(bf16x8*)(wb + (size_t)b * 589824 + i) = ld8f_bf16(srcs[b] + i);
    }
}

// ---------------------------------------------------------------------------
// Kernel 1: fused QKV projection, 512 threads / 8 waves (wave tile 32x64).
// 1-phase gload_lds staging (r14 best-known). q pre-scaled by log2(e).
// Outputs:
//   qr, kr : [((b*12+nh)*1024 + l)*64 + d]
//   v_t    : [((b*12+nh)*64 + d)*1024 + l]
// ---------------------------------------------------------------------------
__global__ __launch_bounds__(512) void qkv_gemm(
    const __hip_bfloat16* __restrict__ xb,
    const __hip_bfloat16* __restrict__ wb,
    const float* __restrict__ bq, const float* __restrict__ bk,
    const float* __restrict__ bv,
    const float* __restrict__ sinp, const float* __restrict__ cosp,
    __hip_bfloat16* __restrict__ qr, __hip_bfloat16* __restrict__ kr,
    __hip_bfloat16* __restrict__ v_t)
{
    __shared__ __align__(16) __hip_bfloat16 Alds[128 * 64];
    __shared__ __align__(16) __hip_bfloat16 Blds[128 * 64];

    const int t    = threadIdx.x;
    const int lane = t & 63;
    const int w    = t >> 6;           // 0..7
    const int wm   = w >> 1, wn = w & 1;
    const int l15  = lane & 15, lhi = lane >> 4;

    const int rm   = blockIdx.x;       // row tile 0..63
    const int cy   = blockIdx.y;       // 0..17
    const int wsel = cy / 6;           // 0=q,1=k,2=v
    const int cn   = cy % 6;

    const __hip_bfloat16* wgt = wb + (size_t)wsel * 589824;
    const float* bias = (wsel == 0) ? bq : (wsel == 1) ? bk : bv;

    const int srow = w * 16 + (lane >> 3);
    const int scol = (lane & 7) * 8;
    const __hip_bfloat16* asrc = xb  + (size_t)(rm * 128 + srow) * 768 + scol;
    const __hip_bfloat16* bsrc = wgt + (size_t)(cn * 128 + srow) * 768 + scol;

    f32x4 acc[2][4] = {};

    for (int k0 = 0; k0 < 768; k0 += 64) {
        __syncthreads();
        #pragma unroll
        for (int j = 0; j < 2; ++j) {
            gload_lds16(asrc + (size_t)j * 8 * 768 + k0, Alds + (w * 2 + j) * 512);
            gload_lds16(bsrc + (size_t)j * 8 * 768 + k0, Blds + (w * 2 + j) * 512);
        }
        __syncthreads();
        #pragma unroll
        for (int kk = 0; kk < 2; ++kk) {
            bf16x8 af[2], bfr[4];
            #pragma unroll
            for (int m = 0; m < 2; ++m)
                af[m] = *(const bf16x8*)&Alds[(wm * 32 + m * 16 + l15) * 64 + kk * 32 + lhi * 8];
            #pragma unroll
            for (int n = 0; n < 4; ++n)
                bfr[n] = *(const bf16x8*)&Blds[(wn * 64 + n * 16 + l15) * 64 + kk * 32 + lhi * 8];
            #pragma unroll
            for (int m = 0; m < 2; ++m)
                #pragma unroll
                for (int n = 0; n < 4; ++n)
                    acc[m][n] = __builtin_amdgcn_mfma_f32_16x16x32_bf16(af[m], bfr[n], acc[m][n], 0, 0, 0);
        }
    }

    // Epilogue: bias, RoPE (q,k), scaling (k: 0.125, q: log2e), scatter.
    #pragma unroll
    for (int m = 0; m < 2; ++m) {
        #pragma unroll
        for (int n = 0; n < 4; ++n) {
            const int gcol = cn * 128 + wn * 64 + n * 16 + l15;   // 0..767
            const float bcol = bias[gcol];
            const int nh = gcol >> 6, d = gcol & 63;
            const int grow0 = rm * 128 + wm * 32 + m * 16 + lhi * 4;
            const int bb = grow0 >> 10, ll0 = grow0 & 1023;
            if (wsel == 2) {
                bf16x4 pk;
                #pragma unroll
                for (int r = 0; r < 4; ++r)
                    ((__hip_bfloat16*)&pk)[r] = __float2bfloat16(acc[m][n][r] + bcol);
                *(bf16x4*)&v_t[(size_t)((bb * 12 + nh) * 64 + d) * 1024 + ll0] = pk;
            } else {
                #pragma unroll
                for (int r = 0; r < 4; ++r) {
                    const int ll = ll0 + r;
                    const float val = acc[m][n][r] + bcol;
                    const float other = __shfl_xor(val, 1);
                    const float cs = cosp[ll * 64 + d];
                    const float sn = sinp[ll * 64 + d];
                    float res = val * cs + ((d & 1) ? other : -other) * sn;
                    res *= (wsel == 1) ? 0.125f : LOG2E;
                    __hip_bfloat16* dst = (wsel == 1) ? kr : qr;
                    dst[(size_t)((bb * 12 + nh) * 1024 + ll) * 64 + d] = __float2bfloat16(res);
                }
            }
        }
    }
}

// ---------------------------------------------------------------------------
// Kernel 2: flash-style attention, swapped-operand, static exp2 softmax,
// mask prefetched one kt ahead. NEW: K/V LDS double-buffered -> ONE block
// barrier per kt (was 2). write(kt+1)->buf^1 can't race compute(kt)->buf;
// write(kt+2)->buf is fenced by barrier(kt+1).
// ---------------------------------------------------------------------------
__global__ __launch_bounds__(256) void attn_kernel(
    const __hip_bfloat16* __restrict__ qr,
    const __hip_bfloat16* __restrict__ kr,
    const __hip_bfloat16* __restrict__ v_t,
    const float* __restrict__ mask,
    __hip_bfloat16* __restrict__ attn_out)
{
    __shared__ __align__(16) __hip_bfloat16 Klds[2][64][LDS_PAD];
    __shared__ __align__(16) __hip_bfloat16 Vtlds[2][64][LDS_PAD];
    __shared__ __align__(16) __hip_bfloat16 Pq[4][16][LDS_PAD];

    const int qt = blockIdx.x;      // 0..15
    const int bh = blockIdx.y;      // 0..95
    const int b = bh / 12, nh = bh % 12;

    const int t = threadIdx.x, lane = t & 63, w = t >> 6;
    const int l15 = lane & 15, lhi = lane >> 4;
    const int qg = qt * 64 + w * 16 + l15;

    bf16x8 qf[2];   // q pre-scaled by log2(e)
    qf[0] = *(const bf16x8*)&qr[((size_t)bh * 1024 + qg) * 64 + lhi * 8];
    qf[1] = *(const bf16x8*)&qr[((size_t)bh * 1024 + qg) * 64 + 32 + lhi * 8];

    f32x4 o[4] = {};
    float l_run = 0.f;

    const int srow = t >> 3;
    const int scol = (t & 7) * 8;

    const float* mbase = mask + ((size_t)nh << 20) + (size_t)qg * 1024;

    // prologue: prefetch kt=0 K/V tiles and mask
    bf16x8 kb0, kb1, vb0, vb1;
    float4 mv[4];
    {
        const size_t kbase = ((size_t)bh * 1024) * 64;
        kb0 = *(const bf16x8*)&kr[kbase + (size_t)srow * 64 + scol];
        kb1 = *(const bf16x8*)&kr[kbase + (size_t)(srow + 32) * 64 + scol];
        const size_t vbase = (size_t)bh * 64 * 1024;
        vb0 = *(const bf16x8*)&v_t[vbase + (size_t)srow * 1024 + scol];
        vb1 = *(const bf16x8*)&v_t[vbase + (size_t)(srow + 32) * 1024 + scol];
        #pragma unroll
        for (int n = 0; n < 4; ++n)
            mv[n] = *(const float4*)&mbase[n * 16 + lhi * 4];
    }

    int cur = 0;
    for (int kt = 0; kt < 16; ++kt) {
        *(bf16x8*)&Klds[cur][srow][scol]       = kb0;
        *(bf16x8*)&Klds[cur][srow + 32][scol]  = kb1;
        *(bf16x8*)&Vtlds[cur][srow][scol]      = vb0;
        *(bf16x8*)&Vtlds[cur][srow + 32][scol] = vb1;
        __syncthreads();   // the ONLY barrier this iteration

        float4 mvn[4];
        if (kt < 15) {   // prefetch next tile's K/V AND mask
            const size_t kbase = ((size_t)bh * 1024 + (kt + 1) * 64) * 64;
            kb0 = *(const bf16x8*)&kr[kbase + (size_t)srow * 64 + scol];
            kb1 = *(const bf16x8*)&kr[kbase + (size_t)(srow + 32) * 64 + scol];
            const size_t vbase = (size_t)bh * 64 * 1024 + (kt + 1) * 64;
            vb0 = *(const bf16x8*)&v_t[vbase + (size_t)srow * 1024 + scol];
            vb1 = *(const bf16x8*)&v_t[vbase + (size_t)(srow + 32) * 1024 + scol];
            #pragma unroll
            for (int n = 0; n < 4; ++n)
                mvn[n] = *(const float4*)&mbase[(kt + 1) * 64 + n * 16 + lhi * 4];
        }

        f32x4 s[4] = {};
        __builtin_amdgcn_s_setprio(1);
        #pragma unroll
        for (int n = 0; n < 4; ++n) {
            const bf16x8 kf0 = *(const bf16x8*)&Klds[cur][n * 16 + l15][lhi * 8];
            const bf16x8 kf1 = *(const bf16x8*)&Klds[cur][n * 16 + l15][32 + lhi * 8];
            s[n] = __builtin_amdgcn_mfma_f32_16x16x32_bf16(kf0, qf[0], s[n], 0, 0, 0);
            s[n] = __builtin_amdgcn_mfma_f32_16x16x32_bf16(kf1, qf[1], s[n], 0, 0, 0);
        }
        __builtin_amdgcn_s_setprio(0);

        // static softmax: P = exp2(s + mask*log2e); pure-sum l accumulation
        #pragma unroll
        for (int n = 0; n < 4; ++n) {
            bf16x4 pk;
            #pragma unroll
            for (int r = 0; r < 4; ++r) {
                const float p = exp2f(fmaf(((const float*)&mv[n])[r], LOG2E, s[n][r]));
                l_run += p;
                ((__hip_bfloat16*)&pk)[r] = __float2bfloat16(p);
            }
            *(bf16x4*)&Pq[w][l15][n * 16 + lhi * 4] = pk;
        }
        asm volatile("s_waitcnt lgkmcnt(0)" ::: "memory");
        __builtin_amdgcn_sched_barrier(0);

        __builtin_amdgcn_s_setprio(1);
        #pragma unroll
        for (int ks = 0; ks < 2; ++ks) {
            const bf16x8 pf = *(const bf16x8*)&Pq[w][l15][ks * 32 + lhi * 8];
            #pragma unroll
            for (int m = 0; m < 4; ++m) {
                const bf16x8 vf = *(const bf16x8*)&Vtlds[cur][m * 16 + l15][ks * 32 + lhi * 8];
                o[m] = __builtin_amdgcn_mfma_f32_16x16x32_bf16(vf, pf, o[m], 0, 0, 0);
            }
        }
        __builtin_amdgcn_s_setprio(0);

        #pragma unroll
        for (int n = 0; n < 4; ++n) mv[n] = mvn[n];
        cur ^= 1;
    }

    // one final cross-lane l reduce (q row spans lhi = 0..3)
    l_run += __shfl_xor(l_run, 16);
    l_run += __shfl_xor(l_run, 32);

    const float rl = 1.f / l_run;
    #pragma unroll
    for (int m = 0; m < 4; ++m) {
        bf16x4 pk;
        #pragma unroll
        for (int r = 0; r < 4; ++r)
            ((__hip_bfloat16*)&pk)[r] = __float2bfloat16(o[m][r] * rl);
        *(bf16x4*)&attn_out[((size_t)b * 1024 + qg) * 768 + nh * 64 + m * 16 + lhi * 4] = pk;
    }
}

// ---------------------------------------------------------------------------
// Kernel 3: depthwise 5x5 conv (LEPE), fused add into aout (in-place).
// ---------------------------------------------------------------------------
__global__ __launch_bounds__(256) void lepe_conv(
    const __hip_bfloat16* __restrict__ v_t,
    const float* __restrict__ lw,
    const float* __restrict__ lb,
    __hip_bfloat16* __restrict__ aout)
{
    __shared__ __hip_bfloat16 img[8][1024];

    const int b  = blockIdx.x / 96;
    const int cg = blockIdx.x % 96;
    const int c0 = cg * 8;
    const int t  = threadIdx.x;

    for (int i = t; i < 2048; i += 256) {
        const int ci = i >> 8, l4 = (i & 255) << 2;
        const int c = c0 + ci, nh = c >> 6, d = c & 63;
        *(bf16x4*)&img[ci][l4] =
            *(const bf16x4*)&v_t[(size_t)((b * 12 + nh) * 64 + d) * 1024 + l4];
    }
    __syncthreads();

    const int ci = t & 7, c = c0 + ci;
    float wt[25];
    #pragma unroll
    for (int k = 0; k < 25; ++k) wt[k] = lw[k * 768 + c];
    const float bias = lb[c];

    for (int l0 = t >> 3; l0 < 1024; l0 += 32) {
        const int h = l0 >> 5, w = l0 & 31;
        float s = bias;
        #pragma unroll
        for (int dy = 0; dy < 5; ++dy) {
            const int hy = h + dy - 2;
            if (hy < 0 || hy > 31) continue;
            #pragma unroll
            for (int dx = 0; dx < 5; ++dx) {
                const int wx = w + dx - 2;
                if (wx < 0 || wx > 31) continue;
                s += bf2f(img[ci][hy * 32 + wx]) * wt[dy * 5 + dx];
            }
        }
        const size_t idx = (size_t)(b * 1024 + l0) * 768 + c;
        aout[idx] = __float2bfloat16(s + bf2f(aout[idx]));
    }
}

// ---------------------------------------------------------------------------
// Kernel 4: output projection (512 threads / 8 waves, wave tile 32x64,
// 1-phase gload_lds staging). out = aout @ wo^T + bo  (bf16 in, f32 out)
// ---------------------------------------------------------------------------
__global__ __launch_bounds__(512) void proj_gemm(
    const __hip_bfloat16* __restrict__ aout,
    const __hip_bfloat16* __restrict__ wb,
    const float* __restrict__ bo,
    float* __restrict__ out)
{
    __shared__ __align__(16) __hip_bfloat16 Alds[128 * 64];
    __shared__ __align__(16) __hip_bfloat16 Blds[128 * 64];

    const int t    = threadIdx.x;
    const int lane = t & 63;
    const int w    = t >> 6;
    const int wm   = w >> 1, wn = w & 1;
    const int l15  = lane & 15, lhi = lane >> 4;

    const int rm = blockIdx.x, cn = blockIdx.y;
    const __hip_bfloat16* wgt = wb + (size_t)3 * 589824;

    const int srow = w * 16 + (lane >> 3);
    const int scol = (lane & 7) * 8;
    const __hip_bfloat16* asrc = aout + (size_t)(rm * 128 + srow) * 768 + scol;
    const __hip_bfloat16* bsrc = wgt  + (size_t)(cn * 128 + srow) * 768 + scol;

    f32x4 acc[2][4] = {};

    for (int k0 = 0; k0 < 768; k0 += 64) {
        __syncthreads();
        #pragma unroll
        for (int j = 0; j < 2; ++j) {
            gload_lds16(asrc + (size_t)j * 8 * 768 + k0, Alds + (w * 2 + j) * 512);
            gload_lds16(bsrc + (size_t)j * 8 * 768 + k0, Blds + (w * 2 + j) * 512);
        }
        __syncthreads();
        #pragma unroll
        for (int kk = 0; kk < 2; ++kk) {
            bf16x8 af[2], bfr[4];
            #pragma unroll
            for (int m = 0; m < 2; ++m)
                af[m] = *(const bf16x8*)&Alds[(wm * 32 + m * 16 + l15) * 64 + kk * 32 + lhi * 8];
            #pragma unroll
            for (int n = 0; n < 4; ++n)
                bfr[n] = *(const bf16x8*)&Blds[(wn * 64 + n * 16 + l15) * 64 + kk * 32 + lhi * 8];
            #pragma unroll
            for (int m = 0; m < 2; ++m)
                #pragma unroll
                for (int n = 0; n < 4; ++n)
                    acc[m][n] = __builtin_amdgcn_mfma_f32_16x16x32_bf16(af[m], bfr[n], acc[m][n], 0, 0, 0);
        }
    }

    #pragma unroll
    for (int m = 0; m < 2; ++m)
        #pragma unroll
        for (int n = 0; n < 4; ++n) {
            const int gcol = cn * 128 + wn * 64 + n * 16 + l15;
            const float bcol = bo[gcol];
            #pragma unroll
            for (int r = 0; r < 4; ++r) {
                const int grow = rm * 128 + wm * 32 + m * 16 + lhi * 4 + r;
                out[(size_t)grow * 768 + gcol] = acc[m][n][r] + bcol;
            }
        }
}

// ---------------------------------------------------------------------------
extern "C" void kernel_launch(void* const* d_in, const int* in_sizes, int n_in,
                              void* d_out, int out_size, void* d_ws, size_t ws_size,
                              hipStream_t stream) {
    const float* x    = (const float*)d_in[0];
    const float* sinp = (const float*)d_in[1];
    const float* cosp = (const float*)d_in[2];
    const float* mask = (const float*)d_in[3];
    const float* wq   = (const float*)d_in[4];
    const float* bq   = (const float*)d_in[5];
    const float* wk   = (const float*)d_in[6];
    const float* bk   = (const float*)d_in[7];
    const float* wvw  = (const float*)d_in[8];
    const float* bv   = (const float*)d_in[9];
    const float* lw   = (const float*)d_in[10];
    const float* lb   = (const float*)d_in[11];
    const float* wo   = (const float*)d_in[12];
    const float* bo   = (const float*)d_in[13];
    float* out = (float*)d_out;

    char* ws = (char*)d_ws;
    const size_t SZ = (size_t)8192 * 768 * 2;    // 12.58 MB per bf16 buffer
    __hip_bfloat16* qr   = (__hip_bfloat16*)(ws);
    __hip_bfloat16* kr   = (__hip_bfloat16*)(ws + SZ);
    __hip_bfloat16* v_t  = (__hip_bfloat16*)(ws + 2 * SZ);
    __hip_bfloat16* xb   = (__hip_bfloat16*)(ws + 3 * SZ);
    __hip_bfloat16* wb   = (__hip_bfloat16*)(ws + 4 * SZ);   // 4x768x768 bf16
    __hip_bfloat16* aout = xb;   // xb dead after qkv_gemm

    cvt_in<<<dim3(4224), 256, 0, stream>>>(x, wq, wk, wvw, wo, xb, wb);
    qkv_gemm<<<dim3(64, 18), 512, 0, stream>>>(xb, wb, bq, bk, bv,
                                               sinp, cosp, qr, kr, v_t);
    attn_kernel<<<dim3(16, 96), 256, 0, stream>>>(qr, kr, v_t, mask, aout);
    lepe_conv<<<dim3(768), 256, 0, stream>>>(v_t, lw, lb, aout);
    proj_gemm<<<dim3(64, 6), 512, 0, stream>>>(aout, wb, bo, out);
}

// Round 18
// 236.960 us; speedup vs baseline: 1.0452x; 1.0041x over previous
//
#include <hip/hip_runtime.h>
#include <hip/hip_bf16.h>

typedef __attribute__((ext_vector_type(8))) short bf16x8;
typedef __attribute__((ext_vector_type(4))) short bf16x4;
typedef __attribute__((ext_vector_type(4))) float f32x4;

#define LDS_PAD 72
#define LOG2E 1.44269504088896f

static __device__ __forceinline__ float bf2f(__hip_bfloat16 v) { return __bfloat162float(v); }

// load 8 consecutive f32, round to bf16x8
static __device__ __forceinline__ bf16x8 ld8f_bf16(const float* __restrict__ p) {
    const float4 a = *(const float4*)p;
    const float4 b = *(const float4*)(p + 4);
    bf16x8 r;
    __hip_bfloat16* h = (__hip_bfloat16*)&r;
    h[0] = __float2bfloat16(a.x); h[1] = __float2bfloat16(a.y);
    h[2] = __float2bfloat16(a.z); h[3] = __float2bfloat16(a.w);
    h[4] = __float2bfloat16(b.x); h[5] = __float2bfloat16(b.y);
    h[6] = __float2bfloat16(b.z); h[7] = __float2bfloat16(b.w);
    return r;
}

// async global->LDS, 16B per lane; lds base must be wave-uniform
static __device__ __forceinline__ void gload_lds16(const __hip_bfloat16* g, __hip_bfloat16* l) {
    __builtin_amdgcn_global_load_lds(
        (const __attribute__((address_space(1))) void*)g,
        (__attribute__((address_space(3))) void*)l, 16, 0, 0);
}

// ---------------------------------------------------------------------------
// Kernel 0: merged f32 -> bf16 conversion (x + the 4 weight matrices).
// ---------------------------------------------------------------------------
__global__ __launch_bounds__(256) void cvt_in(
    const float* __restrict__ x,
    const float* __restrict__ w0, const float* __restrict__ w1,
    const float* __restrict__ w2, const float* __restrict__ w3,
    __hip_bfloat16* __restrict__ xb, __hip_bfloat16* __restrict__ wb)
{
    const int blk = blockIdx.x;
    if (blk < 3072) {
        const int i = (blk * 256 + threadIdx.x) * 8;
        *(bf16x8*)(xb + i) = ld8f_bf16(x + i);
    } else {
        const float* srcs[4] = {w0, w1, w2, w3};
        const int wblk = blk - 3072;
        const int b = wblk / 288;
        const int i = ((wblk % 288) * 256 + threadIdx.x) * 8;
        *(bf16x8*)(wb + (size_t)b * 589824 + i) = ld8f_bf16(srcs[b] + i);
    }
}

// ---------------------------------------------------------------------------
// Kernel 1: fused QKV projection, 512 threads / 8 waves (wave tile 32x64).
// BK=32, 3-deep buffered gload_lds with COUNTED vmcnt(2) + raw s_barrier
// (no vmcnt(0) drain): loads span two compute phases (T3+T4).
// Outputs:
//   qr, kr : [((b*12+nh)*1024 + l)*64 + d]   (q pre-scaled by log2e)
//   v_t    : [((b*12+nh)*64 + d)*1024 + l]
// ---------------------------------------------------------------------------
__global__ __launch_bounds__(512) void qkv_gemm(
    const __hip_bfloat16* __restrict__ xb,
    const __hip_bfloat16* __restrict__ wb,
    const float* __restrict__ bq, const float* __restrict__ bk,
    const float* __restrict__ bv,
    const float* __restrict__ sinp, const float* __restrict__ cosp,
    __hip_bfloat16* __restrict__ qr, __hip_bfloat16* __restrict__ kr,
    __hip_bfloat16* __restrict__ v_t)
{
    __shared__ __align__(16) __hip_bfloat16 Alds[3][128 * 32];   // 48 KB total
    __shared__ __align__(16) __hip_bfloat16 Blds[3][128 * 32];

    const int t    = threadIdx.x;
    const int lane = t & 63;
    const int w    = t >> 6;           // 0..7
    const int wm   = w >> 1, wn = w & 1;
    const int l15  = lane & 15, lhi = lane >> 4;

    const int rm   = blockIdx.x;       // row tile 0..63
    const int cy   = blockIdx.y;       // 0..17
    const int wsel = cy / 6;           // 0=q,1=k,2=v
    const int cn   = cy % 6;

    const __hip_bfloat16* wgt = wb + (size_t)wsel * 589824;
    const float* bias = (wsel == 0) ? bq : (wsel == 1) ? bk : bv;

    // staging: 1 gload per thread per matrix per K-step (BK=32)
    const __hip_bfloat16* asrc = xb  + (size_t)(rm * 128 + w * 16 + (lane >> 2)) * 768 + (lane & 3) * 8;
    const __hip_bfloat16* bsrc = wgt + (size_t)(cn * 128 + w * 16 + (lane >> 2)) * 768 + (lane & 3) * 8;

    f32x4 acc[2][4] = {};

    __hip_bfloat16 *pa0 = Alds[0], *pa1 = Alds[1], *pa2 = Alds[2];
    __hip_bfloat16 *pb0 = Blds[0], *pb1 = Blds[1], *pb2 = Blds[2];

    // prologue: issue steps 0 and 1
    gload_lds16(asrc,      pa0 + w * 512);
    gload_lds16(bsrc,      pb0 + w * 512);
    gload_lds16(asrc + 32, pa1 + w * 512);
    gload_lds16(bsrc + 32, pb1 + w * 512);

    for (int i = 0; i < 24; ++i) {
        // wait for step i's pair only; step i+1's pair stays in flight
        if (i < 23) asm volatile("s_waitcnt vmcnt(2)" ::: "memory");
        else        asm volatile("s_waitcnt vmcnt(0)" ::: "memory");
        __builtin_amdgcn_s_barrier();   // raw barrier: no implicit drain

        if (i + 2 < 24) {
            gload_lds16(asrc + (i + 2) * 32, pa2 + w * 512);
            gload_lds16(bsrc + (i + 2) * 32, pb2 + w * 512);
        }

        // compute step i from buffer 0
        {
            bf16x8 af[2], bfr[4];
            #pragma unroll
            for (int m = 0; m < 2; ++m)
                af[m] = *(const bf16x8*)&pa0[(wm * 32 + m * 16 + l15) * 32 + lhi * 8];
            #pragma unroll
            for (int n = 0; n < 4; ++n)
                bfr[n] = *(const bf16x8*)&pb0[(wn * 64 + n * 16 + l15) * 32 + lhi * 8];
            #pragma unroll
            for (int m = 0; m < 2; ++m)
                #pragma unroll
                for (int n = 0; n < 4; ++n)
                    acc[m][n] = __builtin_amdgcn_mfma_f32_16x16x32_bf16(af[m], bfr[n], acc[m][n], 0, 0, 0);
        }

        // rotate buffers
        __hip_bfloat16* ta = pa0; pa0 = pa1; pa1 = pa2; pa2 = ta;
        __hip_bfloat16* tb = pb0; pb0 = pb1; pb1 = pb2; pb2 = tb;
    }

    // Epilogue: bias, RoPE (q,k), scaling (k: 0.125, q: log2e), scatter.
    #pragma unroll
    for (int m = 0; m < 2; ++m) {
        #pragma unroll
        for (int n = 0; n < 4; ++n) {
            const int gcol = cn * 128 + wn * 64 + n * 16 + l15;   // 0..767
            const float bcol = bias[gcol];
            const int nh = gcol >> 6, d = gcol & 63;
            const int grow0 = rm * 128 + wm * 32 + m * 16 + lhi * 4;
            const int bb = grow0 >> 10, ll0 = grow0 & 1023;
            if (wsel == 2) {
                bf16x4 pk;
                #pragma unroll
                for (int r = 0; r < 4; ++r)
                    ((__hip_bfloat16*)&pk)[r] = __float2bfloat16(acc[m][n][r] + bcol);
                *(bf16x4*)&v_t[(size_t)((bb * 12 + nh) * 64 + d) * 1024 + ll0] = pk;
            } else {
                #pragma unroll
                for (int r = 0; r < 4; ++r) {
                    const int ll = ll0 + r;
                    const float val = acc[m][n][r] + bcol;
                    const float other = __shfl_xor(val, 1);
                    const float cs = cosp[ll * 64 + d];
                    const float sn = sinp[ll * 64 + d];
                    float res = val * cs + ((d & 1) ? other : -other) * sn;
                    res *= (wsel == 1) ? 0.125f : LOG2E;
                    __hip_bfloat16* dst = (wsel == 1) ? kr : qr;
                    dst[(size_t)((bb * 12 + nh) * 1024 + ll) * 64 + d] = __float2bfloat16(res);
                }
            }
        }
    }
}

// ---------------------------------------------------------------------------
// Kernel 2: flash-style attention (r14 best-known: swapped-operand, LDS-staged
// K/V + register prefetch, static exp2 softmax, mask prefetched one kt ahead).
// ---------------------------------------------------------------------------
__global__ __launch_bounds__(256) void attn_kernel(
    const __hip_bfloat16* __restrict__ qr,
    const __hip_bfloat16* __restrict__ kr,
    const __hip_bfloat16* __restrict__ v_t,
    const float* __restrict__ mask,
    __hip_bfloat16* __restrict__ attn_out)
{
    __shared__ __align__(16) __hip_bfloat16 Klds[64][LDS_PAD];
    __shared__ __align__(16) __hip_bfloat16 Vtlds[64][LDS_PAD];
    __shared__ __align__(16) __hip_bfloat16 Pq[4][16][LDS_PAD];

    const int qt = blockIdx.x;      // 0..15
    const int bh = blockIdx.y;      // 0..95
    const int b = bh / 12, nh = bh % 12;

    const int t = threadIdx.x, lane = t & 63, w = t >> 6;
    const int l15 = lane & 15, lhi = lane >> 4;
    const int qg = qt * 64 + w * 16 + l15;

    bf16x8 qf[2];   // q pre-scaled by log2(e)
    qf[0] = *(const bf16x8*)&qr[((size_t)bh * 1024 + qg) * 64 + lhi * 8];
    qf[1] = *(const bf16x8*)&qr[((size_t)bh * 1024 + qg) * 64 + 32 + lhi * 8];

    f32x4 o[4] = {};
    float l_run = 0.f;

    const int srow = t >> 3;
    const int scol = (t & 7) * 8;

    const float* mbase = mask + ((size_t)nh << 20) + (size_t)qg * 1024;

    bf16x8 kb0, kb1, vb0, vb1;
    float4 mv[4];
    {
        const size_t kbase = ((size_t)bh * 1024) * 64;
        kb0 = *(const bf16x8*)&kr[kbase + (size_t)srow * 64 + scol];
        kb1 = *(const bf16x8*)&kr[kbase + (size_t)(srow + 32) * 64 + scol];
        const size_t vbase = (size_t)bh * 64 * 1024;
        vb0 = *(const bf16x8*)&v_t[vbase + (size_t)srow * 1024 + scol];
        vb1 = *(const bf16x8*)&v_t[vbase + (size_t)(srow + 32) * 1024 + scol];
        #pragma unroll
        for (int n = 0; n < 4; ++n)
            mv[n] = *(const float4*)&mbase[n * 16 + lhi * 4];
    }

    for (int kt = 0; kt < 16; ++kt) {
        *(bf16x8*)&Klds[srow][scol]       = kb0;
        *(bf16x8*)&Klds[srow + 32][scol]  = kb1;
        *(bf16x8*)&Vtlds[srow][scol]      = vb0;
        *(bf16x8*)&Vtlds[srow + 32][scol] = vb1;
        __syncthreads();

        float4 mvn[4];
        if (kt < 15) {
            const size_t kbase = ((size_t)bh * 1024 + (kt + 1) * 64) * 64;
            kb0 = *(const bf16x8*)&kr[kbase + (size_t)srow * 64 + scol];
            kb1 = *(const bf16x8*)&kr[kbase + (size_t)(srow + 32) * 64 + scol];
            const size_t vbase = (size_t)bh * 64 * 1024 + (kt + 1) * 64;
            vb0 = *(const bf16x8*)&v_t[vbase + (size_t)srow * 1024 + scol];
            vb1 = *(const bf16x8*)&v_t[vbase + (size_t)(srow + 32) * 1024 + scol];
            #pragma unroll
            for (int n = 0; n < 4; ++n)
                mvn[n] = *(const float4*)&mbase[(kt + 1) * 64 + n * 16 + lhi * 4];
        }

        f32x4 s[4] = {};
        __builtin_amdgcn_s_setprio(1);
        #pragma unroll
        for (int n = 0; n < 4; ++n) {
            const bf16x8 kf0 = *(const bf16x8*)&Klds[n * 16 + l15][lhi * 8];
            const bf16x8 kf1 = *(const bf16x8*)&Klds[n * 16 + l15][32 + lhi * 8];
            s[n] = __builtin_amdgcn_mfma_f32_16x16x32_bf16(kf0, qf[0], s[n], 0, 0, 0);
            s[n] = __builtin_amdgcn_mfma_f32_16x16x32_bf16(kf1, qf[1], s[n], 0, 0, 0);
        }
        __builtin_amdgcn_s_setprio(0);

        #pragma unroll
        for (int n = 0; n < 4; ++n) {
            bf16x4 pk;
            #pragma unroll
            for (int r = 0; r < 4; ++r) {
                const float p = exp2f(fmaf(((const float*)&mv[n])[r], LOG2E, s[n][r]));
                l_run += p;
                ((__hip_bfloat16*)&pk)[r] = __float2bfloat16(p);
            }
            *(bf16x4*)&Pq[w][l15][n * 16 + lhi * 4] = pk;
        }
        asm volatile("s_waitcnt lgkmcnt(0)" ::: "memory");
        __builtin_amdgcn_sched_barrier(0);

        __builtin_amdgcn_s_setprio(1);
        #pragma unroll
        for (int ks = 0; ks < 2; ++ks) {
            const bf16x8 pf = *(const bf16x8*)&Pq[w][l15][ks * 32 + lhi * 8];
            #pragma unroll
            for (int m = 0; m < 4; ++m) {
                const bf16x8 vf = *(const bf16x8*)&Vtlds[m * 16 + l15][ks * 32 + lhi * 8];
                o[m] = __builtin_amdgcn_mfma_f32_16x16x32_bf16(vf, pf, o[m], 0, 0, 0);
            }
        }
        __builtin_amdgcn_s_setprio(0);
        __syncthreads();

        #pragma unroll
        for (int n = 0; n < 4; ++n) mv[n] = mvn[n];
    }

    l_run += __shfl_xor(l_run, 16);
    l_run += __shfl_xor(l_run, 32);

    const float rl = 1.f / l_run;
    #pragma unroll
    for (int m = 0; m < 4; ++m) {
        bf16x4 pk;
        #pragma unroll
        for (int r = 0; r < 4; ++r)
            ((__hip_bfloat16*)&pk)[r] = __float2bfloat16(o[m][r] * rl);
        *(bf16x4*)&attn_out[((size_t)b * 1024 + qg) * 768 + nh * 64 + m * 16 + lhi * 4] = pk;
    }
}

// ---------------------------------------------------------------------------
// Kernel 3: depthwise 5x5 conv (LEPE), fused add into aout (in-place).
// ---------------------------------------------------------------------------
__global__ __launch_bounds__(256) void lepe_conv(
    const __hip_bfloat16* __restrict__ v_t,
    const float* __restrict__ lw,
    const float* __restrict__ lb,
    __hip_bfloat16* __restrict__ aout)
{
    __shared__ __hip_bfloat16 img[8][1024];

    const int b  = blockIdx.x / 96;
    const int cg = blockIdx.x % 96;
    const int c0 = cg * 8;
    const int t  = threadIdx.x;

    for (int i = t; i < 2048; i += 256) {
        const int ci = i >> 8, l4 = (i & 255) << 2;
        const int c = c0 + ci, nh = c >> 6, d = c & 63;
        *(bf16x4*)&img[ci][l4] =
            *(const bf16x4*)&v_t[(size_t)((b * 12 + nh) * 64 + d) * 1024 + l4];
    }
    __syncthreads();

    const int ci = t & 7, c = c0 + ci;
    float wt[25];
    #pragma unroll
    for (int k = 0; k < 25; ++k) wt[k] = lw[k * 768 + c];
    const float bias = lb[c];

    for (int l0 = t >> 3; l0 < 1024; l0 += 32) {
        const int h = l0 >> 5, w = l0 & 31;
        float s = bias;
        #pragma unroll
        for (int dy = 0; dy < 5; ++dy) {
            const int hy = h + dy - 2;
            if (hy < 0 || hy > 31) continue;
            #pragma unroll
            for (int dx = 0; dx < 5; ++dx) {
                const int wx = w + dx - 2;
                if (wx < 0 || wx > 31) continue;
                s += bf2f(img[ci][hy * 32 + wx]) * wt[dy * 5 + dx];
            }
        }
        const size_t idx = (size_t)(b * 1024 + l0) * 768 + c;
        aout[idx] = __float2bfloat16(s + bf2f(aout[idx]));
    }
}

// ---------------------------------------------------------------------------
// Kernel 4: output projection (512 threads / 8 waves, wave tile 32x64,
// 1-phase gload_lds staging). out = aout @ wo^T + bo  (bf16 in, f32 out)
// ---------------------------------------------------------------------------
__global__ __launch_bounds__(512) void proj_gemm(
    const __hip_bfloat16* __restrict__ aout,
    const __hip_bfloat16* __restrict__ wb,
    const float* __restrict__ bo,
    float* __restrict__ out)
{
    __shared__ __align__(16) __hip_bfloat16 Alds[128 * 64];
    __shared__ __align__(16) __hip_bfloat16 Blds[128 * 64];

    const int t    = threadIdx.x;
    const int lane = t & 63;
    const int w    = t >> 6;
    const int wm   = w >> 1, wn = w & 1;
    const int l15  = lane & 15, lhi = lane >> 4;

    const int rm = blockIdx.x, cn = blockIdx.y;
    const __hip_bfloat16* wgt = wb + (size_t)3 * 589824;

    const int srow = w * 16 + (lane >> 3);
    const int scol = (lane & 7) * 8;
    const __hip_bfloat16* asrc = aout + (size_t)(rm * 128 + srow) * 768 + scol;
    const __hip_bfloat16* bsrc = wgt  + (size_t)(cn * 128 + srow) * 768 + scol;

    f32x4 acc[2][4] = {};

    for (int k0 = 0; k0 < 768; k0 += 64) {
        __syncthreads();
        #pragma unroll
        for (int j = 0; j < 2; ++j) {
            gload_lds16(asrc + (size_t)j * 8 * 768 + k0, Alds + (w * 2 + j) * 512);
            gload_lds16(bsrc + (size_t)j * 8 * 768 + k0, Blds + (w * 2 + j) * 512);
        }
        __syncthreads();
        #pragma unroll
        for (int kk = 0; kk < 2; ++kk) {
            bf16x8 af[2], bfr[4];
            #pragma unroll
            for (int m = 0; m < 2; ++m)
                af[m] = *(const bf16x8*)&Alds[(wm * 32 + m * 16 + l15) * 64 + kk * 32 + lhi * 8];
            #pragma unroll
            for (int n = 0; n < 4; ++n)
                bfr[n] = *(const bf16x8*)&Blds[(wn * 64 + n * 16 + l15) * 64 + kk * 32 + lhi * 8];
            #pragma unroll
            for (int m = 0; m < 2; ++m)
                #pragma unroll
                for (int n = 0; n < 4; ++n)
                    acc[m][n] = __builtin_amdgcn_mfma_f32_16x16x32_bf16(af[m], bfr[n], acc[m][n], 0, 0, 0);
        }
    }

    #pragma unroll
    for (int m = 0; m < 2; ++m)
        #pragma unroll
        for (int n = 0; n < 4; ++n) {
            const int gcol = cn * 128 + wn * 64 + n * 16 + l15;
            const float bcol = bo[gcol];
            #pragma unroll
            for (int r = 0; r < 4; ++r) {
                const int grow = rm * 128 + wm * 32 + m * 16 + lhi * 4 + r;
                out[(size_t)grow * 768 + gcol] = acc[m][n][r] + bcol;
            }
        }
}

// ---------------------------------------------------------------------------
extern "C" void kernel_launch(void* const* d_in, const int* in_sizes, int n_in,
                              void* d_out, int out_size, void* d_ws, size_t ws_size,
                              hipStream_t stream) {
    const float* x    = (const float*)d_in[0];
    const float* sinp = (const float*)d_in[1];
    const float* cosp = (const float*)d_in[2];
    const float* mask = (const float*)d_in[3];
    const float* wq   = (const float*)d_in[4];
    const float* bq   = (const float*)d_in[5];
    const float* wk   = (const float*)d_in[6];
    const float* bk   = (const float*)d_in[7];
    const float* wvw  = (const float*)d_in[8];
    const float* bv   = (const float*)d_in[9];
    const float* lw   = (const float*)d_in[10];
    const float* lb   = (const float*)d_in[11];
    const float* wo   = (const float*)d_in[12];
    const float* bo   = (const float*)d_in[13];
    float* out = (float*)d_out;

    char* ws = (char*)d_ws;
    const size_t SZ = (size_t)8192 * 768 * 2;    // 12.58 MB per bf16 buffer
    __hip_bfloat16* qr   = (__hip_bfloat16*)(ws);
    __hip_bfloat16* kr   = (__hip_bfloat16*)(ws + SZ);
    __hip_bfloat16* v_t  = (__hip_bfloat16*)(ws + 2 * SZ);
    __hip_bfloat16* xb   = (__hip_bfloat16*)(ws + 3 * SZ);
    __hip_bfloat16* wb   = (__hip_bfloat16*)(ws + 4 * SZ);   // 4x768x768 bf16
    __hip_bfloat16* aout = xb;   // xb dead after qkv_gemm

    cvt_in<<<dim3(4224), 256, 0, stream>>>(x, wq, wk, wvw, wo, xb, wb);
    qkv_gemm<<<dim3(64, 18), 512, 0, stream>>>(xb, wb, bq, bk, bv,
                                               sinp, cosp, qr, kr, v_t);
    attn_kernel<<<dim3(16, 96), 256, 0, stream>>>(qr, kr, v_t, mask, aout);
    lepe_conv<<<dim3(768), 256, 0, stream>>>(v_t, lw, lb, aout);
    proj_gemm<<<dim3(64, 6), 512, 0, stream>>>(aout, wb, bo, out);
}

// Round 19
// 232.627 us; speedup vs baseline: 1.0647x; 1.0186x over previous
//
#include <hip/hip_runtime.h>
#include <hip/hip_bf16.h>

typedef __attribute__((ext_vector_type(8))) short bf16x8;
typedef __attribute__((ext_vector_type(4))) short bf16x4;
typedef __attribute__((ext_vector_type(4))) float f32x4;

#define LDS_PAD 72
#define LOG2E 1.44269504088896f

static __device__ __forceinline__ float bf2f(__hip_bfloat16 v) { return __bfloat162float(v); }

// load 8 consecutive f32, round to bf16x8
static __device__ __forceinline__ bf16x8 ld8f_bf16(const float* __restrict__ p) {
    const float4 a = *(const float4*)p;
    const float4 b = *(const float4*)(p + 4);
    bf16x8 r;
    __hip_bfloat16* h = (__hip_bfloat16*)&r;
    h[0] = __float2bfloat16(a.x); h[1] = __float2bfloat16(a.y);
    h[2] = __float2bfloat16(a.z); h[3] = __float2bfloat16(a.w);
    h[4] = __float2bfloat16(b.x); h[5] = __float2bfloat16(b.y);
    h[6] = __float2bfloat16(b.z); h[7] = __float2bfloat16(b.w);
    return r;
}

// async global->LDS, 16B per lane; lds base must be wave-uniform
static __device__ __forceinline__ void gload_lds16(const __hip_bfloat16* g, __hip_bfloat16* l) {
    __builtin_amdgcn_global_load_lds(
        (const __attribute__((address_space(1))) void*)g,
        (__attribute__((address_space(3))) void*)l, 16, 0, 0);
}

// ---------------------------------------------------------------------------
// Kernel 0: merged f32 -> bf16 conversion (x + the 4 weight matrices).
// ---------------------------------------------------------------------------
__global__ __launch_bounds__(256) void cvt_in(
    const float* __restrict__ x,
    const float* __restrict__ w0, const float* __restrict__ w1,
    const float* __restrict__ w2, const float* __restrict__ w3,
    __hip_bfloat16* __restrict__ xb, __hip_bfloat16* __restrict__ wb)
{
    const int blk = blockIdx.x;
    if (blk < 3072) {
        const int i = (blk * 256 + threadIdx.x) * 8;
        *(bf16x8*)(xb + i) = ld8f_bf16(x + i);
    } else {
        const float* srcs[4] = {w0, w1, w2, w3};
        const int wblk = blk - 3072;
        const int b = wblk / 288;
        const int i = ((wblk % 288) * 256 + threadIdx.x) * 8;
        *(bf16x8*)(wb + (size_t)b * 589824 + i) = ld8f_bf16(srcs[b] + i);
    }
}

// ---------------------------------------------------------------------------
// Kernel 1: fused QKV projection, 512 threads / 8 waves (wave tile 32x64).
// BK=32, 3-deep buffered gload_lds with counted vmcnt(2) + raw s_barrier.
// Outputs:
//   qr, kr : [((b*12+nh)*1024 + l)*64 + d]   (q pre-scaled by log2e)
//   v_t    : [((b*12+nh)*64 + d)*1024 + l]
// ---------------------------------------------------------------------------
__global__ __launch_bounds__(512) void qkv_gemm(
    const __hip_bfloat16* __restrict__ xb,
    const __hip_bfloat16* __restrict__ wb,
    const float* __restrict__ bq, const float* __restrict__ bk,
    const float* __restrict__ bv,
    const float* __restrict__ sinp, const float* __restrict__ cosp,
    __hip_bfloat16* __restrict__ qr, __hip_bfloat16* __restrict__ kr,
    __hip_bfloat16* __restrict__ v_t)
{
    __shared__ __align__(16) __hip_bfloat16 Alds[3][128 * 32];
    __shared__ __align__(16) __hip_bfloat16 Blds[3][128 * 32];

    const int t    = threadIdx.x;
    const int lane = t & 63;
    const int w    = t >> 6;           // 0..7
    const int wm   = w >> 1, wn = w & 1;
    const int l15  = lane & 15, lhi = lane >> 4;

    const int rm   = blockIdx.x;       // row tile 0..63
    const int cy   = blockIdx.y;       // 0..17
    const int wsel = cy / 6;           // 0=q,1=k,2=v
    const int cn   = cy % 6;

    const __hip_bfloat16* wgt = wb + (size_t)wsel * 589824;
    const float* bias = (wsel == 0) ? bq : (wsel == 1) ? bk : bv;

    const __hip_bfloat16* asrc = xb  + (size_t)(rm * 128 + w * 16 + (lane >> 2)) * 768 + (lane & 3) * 8;
    const __hip_bfloat16* bsrc = wgt + (size_t)(cn * 128 + w * 16 + (lane >> 2)) * 768 + (lane & 3) * 8;

    f32x4 acc[2][4] = {};

    __hip_bfloat16 *pa0 = Alds[0], *pa1 = Alds[1], *pa2 = Alds[2];
    __hip_bfloat16 *pb0 = Blds[0], *pb1 = Blds[1], *pb2 = Blds[2];

    gload_lds16(asrc,      pa0 + w * 512);
    gload_lds16(bsrc,      pb0 + w * 512);
    gload_lds16(asrc + 32, pa1 + w * 512);
    gload_lds16(bsrc + 32, pb1 + w * 512);

    for (int i = 0; i < 24; ++i) {
        if (i < 23) asm volatile("s_waitcnt vmcnt(2)" ::: "memory");
        else        asm volatile("s_waitcnt vmcnt(0)" ::: "memory");
        __builtin_amdgcn_s_barrier();

        if (i + 2 < 24) {
            gload_lds16(asrc + (i + 2) * 32, pa2 + w * 512);
            gload_lds16(bsrc + (i + 2) * 32, pb2 + w * 512);
        }

        {
            bf16x8 af[2], bfr[4];
            #pragma unroll
            for (int m = 0; m < 2; ++m)
                af[m] = *(const bf16x8*)&pa0[(wm * 32 + m * 16 + l15) * 32 + lhi * 8];
            #pragma unroll
            for (int n = 0; n < 4; ++n)
                bfr[n] = *(const bf16x8*)&pb0[(wn * 64 + n * 16 + l15) * 32 + lhi * 8];
            #pragma unroll
            for (int m = 0; m < 2; ++m)
                #pragma unroll
                for (int n = 0; n < 4; ++n)
                    acc[m][n] = __builtin_amdgcn_mfma_f32_16x16x32_bf16(af[m], bfr[n], acc[m][n], 0, 0, 0);
        }

        __hip_bfloat16* ta = pa0; pa0 = pa1; pa1 = pa2; pa2 = ta;
        __hip_bfloat16* tb = pb0; pb0 = pb1; pb1 = pb2; pb2 = tb;
    }

    #pragma unroll
    for (int m = 0; m < 2; ++m) {
        #pragma unroll
        for (int n = 0; n < 4; ++n) {
            const int gcol = cn * 128 + wn * 64 + n * 16 + l15;   // 0..767
            const float bcol = bias[gcol];
            const int nh = gcol >> 6, d = gcol & 63;
            const int grow0 = rm * 128 + wm * 32 + m * 16 + lhi * 4;
            const int bb = grow0 >> 10, ll0 = grow0 & 1023;
            if (wsel == 2) {
                bf16x4 pk;
                #pragma unroll
                for (int r = 0; r < 4; ++r)
                    ((__hip_bfloat16*)&pk)[r] = __float2bfloat16(acc[m][n][r] + bcol);
                *(bf16x4*)&v_t[(size_t)((bb * 12 + nh) * 64 + d) * 1024 + ll0] = pk;
            } else {
                #pragma unroll
                for (int r = 0; r < 4; ++r) {
                    const int ll = ll0 + r;
                    const float val = acc[m][n][r] + bcol;
                    const float other = __shfl_xor(val, 1);
                    const float cs = cosp[ll * 64 + d];
                    const float sn = sinp[ll * 64 + d];
                    float res = val * cs + ((d & 1) ? other : -other) * sn;
                    res *= (wsel == 1) ? 0.125f : LOG2E;
                    __hip_bfloat16* dst = (wsel == 1) ? kr : qr;
                    dst[(size_t)((bb * 12 + nh) * 1024 + ll) * 64 + d] = __float2bfloat16(res);
                }
            }
        }
    }
}

// ---------------------------------------------------------------------------
// Kernel 2: FUSED attention + LEPE conv.
// blocks 0..1535  : flash attention (r14/r18 best-known structure), writes aout
// blocks 1536..2303: depthwise 5x5 conv from v_t -> lepeb (independent of attn;
//                    fills attn's scheduling tail instead of a serial dispatch)
// ---------------------------------------------------------------------------
__global__ __launch_bounds__(256) void attn_lepe(
    const __hip_bfloat16* __restrict__ qr,
    const __hip_bfloat16* __restrict__ kr,
    const __hip_bfloat16* __restrict__ v_t,
    const float* __restrict__ mask,
    const float* __restrict__ lw,
    const float* __restrict__ lb,
    __hip_bfloat16* __restrict__ attn_out,
    __hip_bfloat16* __restrict__ lepeb)
{
    __shared__ __align__(16) __hip_bfloat16 Klds[64][LDS_PAD];
    __shared__ __align__(16) __hip_bfloat16 Vtlds[64][LDS_PAD];
    __shared__ __align__(16) __hip_bfloat16 Pq[4][16][LDS_PAD];

    const int blk = blockIdx.x;
    const int t = threadIdx.x;

    if (blk >= 1536) {
        // ----------------- LEPE path -----------------
        __hip_bfloat16 (*img)[1024] = (__hip_bfloat16(*)[1024])Klds;  // reuse LDS (16 KB)
        const int lbk = blk - 1536;
        const int b  = lbk / 96;
        const int cg = lbk % 96;
        const int c0 = cg * 8;

        for (int i = t; i < 2048; i += 256) {
            const int ci = i >> 8, l4 = (i & 255) << 2;
            const int c = c0 + ci, nh = c >> 6, d = c & 63;
            *(bf16x4*)&img[ci][l4] =
                *(const bf16x4*)&v_t[(size_t)((b * 12 + nh) * 64 + d) * 1024 + l4];
        }
        __syncthreads();

        const int ci = t & 7, c = c0 + ci;
        float wt[25];
        #pragma unroll
        for (int k = 0; k < 25; ++k) wt[k] = lw[k * 768 + c];
        const float bias = lb[c];

        for (int l0 = t >> 3; l0 < 1024; l0 += 32) {
            const int h = l0 >> 5, w = l0 & 31;
            float s = bias;
            #pragma unroll
            for (int dy = 0; dy < 5; ++dy) {
                const int hy = h + dy - 2;
                if (hy < 0 || hy > 31) continue;
                #pragma unroll
                for (int dx = 0; dx < 5; ++dx) {
                    const int wx = w + dx - 2;
                    if (wx < 0 || wx > 31) continue;
                    s += bf2f(img[ci][hy * 32 + wx]) * wt[dy * 5 + dx];
                }
            }
            lepeb[(size_t)(b * 1024 + l0) * 768 + c] = __float2bfloat16(s);
        }
        return;
    }

    // ----------------- attention path -----------------
    const int qt = blk & 15;        // 0..15
    const int bh = blk >> 4;        // 0..95
    const int b = bh / 12, nh = bh % 12;

    const int lane = t & 63, w = t >> 6;
    const int l15 = lane & 15, lhi = lane >> 4;
    const int qg = qt * 64 + w * 16 + l15;

    bf16x8 qf[2];   // q pre-scaled by log2(e)
    qf[0] = *(const bf16x8*)&qr[((size_t)bh * 1024 + qg) * 64 + lhi * 8];
    qf[1] = *(const bf16x8*)&qr[((size_t)bh * 1024 + qg) * 64 + 32 + lhi * 8];

    f32x4 o[4] = {};
    float l_run = 0.f;

    const int srow = t >> 3;
    const int scol = (t & 7) * 8;

    const float* mbase = mask + ((size_t)nh << 20) + (size_t)qg * 1024;

    bf16x8 kb0, kb1, vb0, vb1;
    float4 mv[4];
    {
        const size_t kbase = ((size_t)bh * 1024) * 64;
        kb0 = *(const bf16x8*)&kr[kbase + (size_t)srow * 64 + scol];
        kb1 = *(const bf16x8*)&kr[kbase + (size_t)(srow + 32) * 64 + scol];
        const size_t vbase = (size_t)bh * 64 * 1024;
        vb0 = *(const bf16x8*)&v_t[vbase + (size_t)srow * 1024 + scol];
        vb1 = *(const bf16x8*)&v_t[vbase + (size_t)(srow + 32) * 1024 + scol];
        #pragma unroll
        for (int n = 0; n < 4; ++n)
            mv[n] = *(const float4*)&mbase[n * 16 + lhi * 4];
    }

    for (int kt = 0; kt < 16; ++kt) {
        *(bf16x8*)&Klds[srow][scol]       = kb0;
        *(bf16x8*)&Klds[srow + 32][scol]  = kb1;
        *(bf16x8*)&Vtlds[srow][scol]      = vb0;
        *(bf16x8*)&Vtlds[srow + 32][scol] = vb1;
        __syncthreads();

        float4 mvn[4];
        if (kt < 15) {
            const size_t kbase = ((size_t)bh * 1024 + (kt + 1) * 64) * 64;
            kb0 = *(const bf16x8*)&kr[kbase + (size_t)srow * 64 + scol];
            kb1 = *(const bf16x8*)&kr[kbase + (size_t)(srow + 32) * 64 + scol];
            const size_t vbase = (size_t)bh * 64 * 1024 + (kt + 1) * 64;
            vb0 = *(const bf16x8*)&v_t[vbase + (size_t)srow * 1024 + scol];
            vb1 = *(const bf16x8*)&v_t[vbase + (size_t)(srow + 32) * 1024 + scol];
            #pragma unroll
            for (int n = 0; n < 4; ++n)
                mvn[n] = *(const float4*)&mbase[(kt + 1) * 64 + n * 16 + lhi * 4];
        }

        f32x4 s[4] = {};
        __builtin_amdgcn_s_setprio(1);
        #pragma unroll
        for (int n = 0; n < 4; ++n) {
            const bf16x8 kf0 = *(const bf16x8*)&Klds[n * 16 + l15][lhi * 8];
            const bf16x8 kf1 = *(const bf16x8*)&Klds[n * 16 + l15][32 + lhi * 8];
            s[n] = __builtin_amdgcn_mfma_f32_16x16x32_bf16(kf0, qf[0], s[n], 0, 0, 0);
            s[n] = __builtin_amdgcn_mfma_f32_16x16x32_bf16(kf1, qf[1], s[n], 0, 0, 0);
        }
        __builtin_amdgcn_s_setprio(0);

        #pragma unroll
        for (int n = 0; n < 4; ++n) {
            bf16x4 pk;
            #pragma unroll
            for (int r = 0; r < 4; ++r) {
                const float p = exp2f(fmaf(((const float*)&mv[n])[r], LOG2E, s[n][r]));
                l_run += p;
                ((__hip_bfloat16*)&pk)[r] = __float2bfloat16(p);
            }
            *(bf16x4*)&Pq[w][l15][n * 16 + lhi * 4] = pk;
        }
        asm volatile("s_waitcnt lgkmcnt(0)" ::: "memory");
        __builtin_amdgcn_sched_barrier(0);

        __builtin_amdgcn_s_setprio(1);
        #pragma unroll
        for (int ks = 0; ks < 2; ++ks) {
            const bf16x8 pf = *(const bf16x8*)&Pq[w][l15][ks * 32 + lhi * 8];
            #pragma unroll
            for (int m = 0; m < 4; ++m) {
                const bf16x8 vf = *(const bf16x8*)&Vtlds[m * 16 + l15][ks * 32 + lhi * 8];
                o[m] = __builtin_amdgcn_mfma_f32_16x16x32_bf16(vf, pf, o[m], 0, 0, 0);
            }
        }
        __builtin_amdgcn_s_setprio(0);
        __syncthreads();

        #pragma unroll
        for (int n = 0; n < 4; ++n) mv[n] = mvn[n];
    }

    l_run += __shfl_xor(l_run, 16);
    l_run += __shfl_xor(l_run, 32);

    const float rl = 1.f / l_run;
    #pragma unroll
    for (int m = 0; m < 4; ++m) {
        bf16x4 pk;
        #pragma unroll
        for (int r = 0; r < 4; ++r)
            ((__hip_bfloat16*)&pk)[r] = __float2bfloat16(o[m][r] * rl);
        *(bf16x4*)&attn_out[((size_t)b * 1024 + qg) * 768 + nh * 64 + m * 16 + lhi * 4] = pk;
    }
}

// ---------------------------------------------------------------------------
// Kernel 3: output projection: out = (aout + lepeb) @ wo^T + bo.
// 512 threads / 8 waves, wave tile 32x64. A reg-staged with fused add
// (prefetched one K-step ahead); B via gload_lds.
// ---------------------------------------------------------------------------
__global__ __launch_bounds__(512) void proj_gemm(
    const __hip_bfloat16* __restrict__ aout,
    const __hip_bfloat16* __restrict__ lepeb,
    const __hip_bfloat16* __restrict__ wb,
    const float* __restrict__ bo,
    float* __restrict__ out)
{
    __shared__ __align__(16) __hip_bfloat16 Alds[128 * 64];
    __shared__ __align__(16) __hip_bfloat16 Blds[128 * 64];

    const int t    = threadIdx.x;
    const int lane = t & 63;
    const int w    = t >> 6;
    const int wm   = w >> 1, wn = w & 1;
    const int l15  = lane & 15, lhi = lane >> 4;

    const int rm = blockIdx.x, cn = blockIdx.y;
    const __hip_bfloat16* wgt = wb + (size_t)3 * 589824;

    const int srow = w * 16 + (lane >> 3);
    const int scol = (lane & 7) * 8;
    const size_t aoff0 = (size_t)(rm * 128 + srow) * 768 + scol;
    const __hip_bfloat16* bsrc = wgt + (size_t)(cn * 128 + srow) * 768 + scol;
    const int lds_off = srow * 64 + scol;

    f32x4 acc[2][4] = {};

    // prologue: load + add first A tile
    bf16x8 ar[2];
    #pragma unroll
    for (int j = 0; j < 2; ++j) {
        const size_t off = aoff0 + (size_t)j * 8 * 768;
        const bf16x8 a1 = *(const bf16x8*)&aout[off];
        const bf16x8 a2 = *(const bf16x8*)&lepeb[off];
        #pragma unroll
        for (int e = 0; e < 8; ++e)
            ((__hip_bfloat16*)&ar[j])[e] = __float2bfloat16(
                bf2f(((const __hip_bfloat16*)&a1)[e]) + bf2f(((const __hip_bfloat16*)&a2)[e]));
    }

    for (int k0 = 0; k0 < 768; k0 += 64) {
        __syncthreads();
        #pragma unroll
        for (int j = 0; j < 2; ++j)
            *(bf16x8*)&Alds[lds_off + j * 8 * 64] = ar[j];
        #pragma unroll
        for (int j = 0; j < 2; ++j)
            gload_lds16(bsrc + (size_t)j * 8 * 768 + k0, Blds + (w * 2 + j) * 512);
        __syncthreads();

        if (k0 + 64 < 768) {
            #pragma unroll
            for (int j = 0; j < 2; ++j) {
                const size_t off = aoff0 + (size_t)j * 8 * 768 + k0 + 64;
                const bf16x8 a1 = *(const bf16x8*)&aout[off];
                const bf16x8 a2 = *(const bf16x8*)&lepeb[off];
                #pragma unroll
                for (int e = 0; e < 8; ++e)
                    ((__hip_bfloat16*)&ar[j])[e] = __float2bfloat16(
                        bf2f(((const __hip_bfloat16*)&a1)[e]) + bf2f(((const __hip_bfloat16*)&a2)[e]));
            }
        }

        #pragma unroll
        for (int kk = 0; kk < 2; ++kk) {
            bf16x8 af[2], bfr[4];
            #pragma unroll
            for (int m = 0; m < 2; ++m)
                af[m] = *(const bf16x8*)&Alds[(wm * 32 + m * 16 + l15) * 64 + kk * 32 + lhi * 8];
            #pragma unroll
            for (int n = 0; n < 4; ++n)
                bfr[n] = *(const bf16x8*)&Blds[(wn * 64 + n * 16 + l15) * 64 + kk * 32 + lhi * 8];
            #pragma unroll
            for (int m = 0; m < 2; ++m)
                #pragma unroll
                for (int n = 0; n < 4; ++n)
                    acc[m][n] = __builtin_amdgcn_mfma_f32_16x16x32_bf16(af[m], bfr[n], acc[m][n], 0, 0, 0);
        }
    }

    #pragma unroll
    for (int m = 0; m < 2; ++m)
        #pragma unroll
        for (int n = 0; n < 4; ++n) {
            const int gcol = cn * 128 + wn * 64 + n * 16 + l15;
            const float bcol = bo[gcol];
            #pragma unroll
            for (int r = 0; r < 4; ++r) {
                const int grow = rm * 128 + wm * 32 + m * 16 + lhi * 4 + r;
                out[(size_t)grow * 768 + gcol] = acc[m][n][r] + bcol;
            }
        }
}

// ---------------------------------------------------------------------------
extern "C" void kernel_launch(void* const* d_in, const int* in_sizes, int n_in,
                              void* d_out, int out_size, void* d_ws, size_t ws_size,
                              hipStream_t stream) {
    const float* x    = (const float*)d_in[0];
    const float* sinp = (const float*)d_in[1];
    const float* cosp = (const float*)d_in[2];
    const float* mask = (const float*)d_in[3];
    const float* wq   = (const float*)d_in[4];
    const float* bq   = (const float*)d_in[5];
    const float* wk   = (const float*)d_in[6];
    const float* bk   = (const float*)d_in[7];
    const float* wvw  = (const float*)d_in[8];
    const float* bv   = (const float*)d_in[9];
    const float* lw   = (const float*)d_in[10];
    const float* lb   = (const float*)d_in[11];
    const float* wo   = (const float*)d_in[12];
    const float* bo   = (const float*)d_in[13];
    float* out = (float*)d_out;

    char* ws = (char*)d_ws;
    const size_t SZ = (size_t)8192 * 768 * 2;    // 12.58 MB per bf16 buffer
    __hip_bfloat16* qr    = (__hip_bfloat16*)(ws);
    __hip_bfloat16* kr    = (__hip_bfloat16*)(ws + SZ);
    __hip_bfloat16* v_t   = (__hip_bfloat16*)(ws + 2 * SZ);
    __hip_bfloat16* xb    = (__hip_bfloat16*)(ws + 3 * SZ);
    __hip_bfloat16* wb    = (__hip_bfloat16*)(ws + 4 * SZ);             // 4.5 MB
    __hip_bfloat16* lepeb = (__hip_bfloat16*)(ws + 4 * SZ + 4718592);   // 12.58 MB
    __hip_bfloat16* aout  = xb;   // xb dead after qkv_gemm

    cvt_in<<<dim3(4224), 256, 0, stream>>>(x, wq, wk, wvw, wo, xb, wb);
    qkv_gemm<<<dim3(64, 18), 512, 0, stream>>>(xb, wb, bq, bk, bv,
                                               sinp, cosp, qr, kr, v_t);
    attn_lepe<<<dim3(2304), 256, 0, stream>>>(qr, kr, v_t, mask, lw, lb, aout, lepeb);
    proj_gemm<<<dim3(64, 6), 512, 0, stream>>>(aout, lepeb, wb, bo, out);
}

// Round 20
// 204.509 us; speedup vs baseline: 1.2111x; 1.1375x over previous
//
#include <hip/hip_runtime.h>
#include <hip/hip_bf16.h>

typedef __attribute__((ext_vector_type(8))) short bf16x8;
typedef __attribute__((ext_vector_type(4))) short bf16x4;
typedef __attribute__((ext_vector_type(4))) float f32x4;

#define LDS_PAD 72
#define LOG2E 1.44269504088896f

static __device__ __forceinline__ float bf2f(__hip_bfloat16 v) { return __bfloat162float(v); }

// load 8 consecutive f32, round to bf16x8
static __device__ __forceinline__ bf16x8 ld8f_bf16(const float* __restrict__ p) {
    const float4 a = *(const float4*)p;
    const float4 b = *(const float4*)(p + 4);
    bf16x8 r;
    __hip_bfloat16* h = (__hip_bfloat16*)&r;
    h[0] = __float2bfloat16(a.x); h[1] = __float2bfloat16(a.y);
    h[2] = __float2bfloat16(a.z); h[3] = __float2bfloat16(a.w);
    h[4] = __float2bfloat16(b.x); h[5] = __float2bfloat16(b.y);
    h[6] = __float2bfloat16(b.z); h[7] = __float2bfloat16(b.w);
    return r;
}

// async global->LDS, 16B per lane; lds base must be wave-uniform
static __device__ __forceinline__ void gload_lds16(const __hip_bfloat16* g, __hip_bfloat16* l) {
    __builtin_amdgcn_global_load_lds(
        (const __attribute__((address_space(1))) void*)g,
        (__attribute__((address_space(3))) void*)l, 16, 0, 0);
}

// ---------------------------------------------------------------------------
// Kernel 0: merged f32 -> bf16 conversion (x + the 4 weight matrices).
// ---------------------------------------------------------------------------
__global__ __launch_bounds__(256) void cvt_in(
    const float* __restrict__ x,
    const float* __restrict__ w0, const float* __restrict__ w1,
    const float* __restrict__ w2, const float* __restrict__ w3,
    __hip_bfloat16* __restrict__ xb, __hip_bfloat16* __restrict__ wb)
{
    const int blk = blockIdx.x;
    if (blk < 3072) {
        const int i = (blk * 256 + threadIdx.x) * 8;
        *(bf16x8*)(xb + i) = ld8f_bf16(x + i);
    } else {
        const float* srcs[4] = {w0, w1, w2, w3};
        const int wblk = blk - 3072;
        const int b = wblk / 288;
        const int i = ((wblk % 288) * 256 + threadIdx.x) * 8;
        *(bf16x8*)(wb + (size_t)b * 589824 + i) = ld8f_bf16(srcs[b] + i);
    }
}

// ---------------------------------------------------------------------------
// Kernel 1: fused QKV projection, 512 threads / 8 waves (wave tile 32x64).
// BK=32, 3-deep buffered gload_lds with counted vmcnt(2) + raw s_barrier.
// Outputs:
//   qr, kr : [((b*12+nh)*1024 + l)*64 + d]   (q pre-scaled by log2e)
//   v_t    : [((b*12+nh)*64 + d)*1024 + l]
// ---------------------------------------------------------------------------
__global__ __launch_bounds__(512) void qkv_gemm(
    const __hip_bfloat16* __restrict__ xb,
    const __hip_bfloat16* __restrict__ wb,
    const float* __restrict__ bq, const float* __restrict__ bk,
    const float* __restrict__ bv,
    const float* __restrict__ sinp, const float* __restrict__ cosp,
    __hip_bfloat16* __restrict__ qr, __hip_bfloat16* __restrict__ kr,
    __hip_bfloat16* __restrict__ v_t)
{
    __shared__ __align__(16) __hip_bfloat16 Alds[3][128 * 32];
    __shared__ __align__(16) __hip_bfloat16 Blds[3][128 * 32];

    const int t    = threadIdx.x;
    const int lane = t & 63;
    const int w    = t >> 6;           // 0..7
    const int wm   = w >> 1, wn = w & 1;
    const int l15  = lane & 15, lhi = lane >> 4;

    const int rm   = blockIdx.x;       // row tile 0..63
    const int cy   = blockIdx.y;       // 0..17
    const int wsel = cy / 6;           // 0=q,1=k,2=v
    const int cn   = cy % 6;

    const __hip_bfloat16* wgt = wb + (size_t)wsel * 589824;
    const float* bias = (wsel == 0) ? bq : (wsel == 1) ? bk : bv;

    const __hip_bfloat16* asrc = xb  + (size_t)(rm * 128 + w * 16 + (lane >> 2)) * 768 + (lane & 3) * 8;
    const __hip_bfloat16* bsrc = wgt + (size_t)(cn * 128 + w * 16 + (lane >> 2)) * 768 + (lane & 3) * 8;

    f32x4 acc[2][4] = {};

    __hip_bfloat16 *pa0 = Alds[0], *pa1 = Alds[1], *pa2 = Alds[2];
    __hip_bfloat16 *pb0 = Blds[0], *pb1 = Blds[1], *pb2 = Blds[2];

    gload_lds16(asrc,      pa0 + w * 512);
    gload_lds16(bsrc,      pb0 + w * 512);
    gload_lds16(asrc + 32, pa1 + w * 512);
    gload_lds16(bsrc + 32, pb1 + w * 512);

    for (int i = 0; i < 24; ++i) {
        if (i < 23) asm volatile("s_waitcnt vmcnt(2)" ::: "memory");
        else        asm volatile("s_waitcnt vmcnt(0)" ::: "memory");
        __builtin_amdgcn_s_barrier();

        if (i + 2 < 24) {
            gload_lds16(asrc + (i + 2) * 32, pa2 + w * 512);
            gload_lds16(bsrc + (i + 2) * 32, pb2 + w * 512);
        }

        {
            bf16x8 af[2], bfr[4];
            #pragma unroll
            for (int m = 0; m < 2; ++m)
                af[m] = *(const bf16x8*)&pa0[(wm * 32 + m * 16 + l15) * 32 + lhi * 8];
            #pragma unroll
            for (int n = 0; n < 4; ++n)
                bfr[n] = *(const bf16x8*)&pb0[(wn * 64 + n * 16 + l15) * 32 + lhi * 8];
            #pragma unroll
            for (int m = 0; m < 2; ++m)
                #pragma unroll
                for (int n = 0; n < 4; ++n)
                    acc[m][n] = __builtin_amdgcn_mfma_f32_16x16x32_bf16(af[m], bfr[n], acc[m][n], 0, 0, 0);
        }

        __hip_bfloat16* ta = pa0; pa0 = pa1; pa1 = pa2; pa2 = ta;
        __hip_bfloat16* tb = pb0; pb0 = pb1; pb1 = pb2; pb2 = tb;
    }

    #pragma unroll
    for (int m = 0; m < 2; ++m) {
        #pragma unroll
        for (int n = 0; n < 4; ++n) {
            const int gcol = cn * 128 + wn * 64 + n * 16 + l15;   // 0..767
            const float bcol = bias[gcol];
            const int nh = gcol >> 6, d = gcol & 63;
            const int grow0 = rm * 128 + wm * 32 + m * 16 + lhi * 4;
            const int bb = grow0 >> 10, ll0 = grow0 & 1023;
            if (wsel == 2) {
                bf16x4 pk;
                #pragma unroll
                for (int r = 0; r < 4; ++r)
                    ((__hip_bfloat16*)&pk)[r] = __float2bfloat16(acc[m][n][r] + bcol);
                *(bf16x4*)&v_t[(size_t)((bb * 12 + nh) * 64 + d) * 1024 + ll0] = pk;
            } else {
                #pragma unroll
                for (int r = 0; r < 4; ++r) {
                    const int ll = ll0 + r;
                    const float val = acc[m][n][r] + bcol;
                    const float other = __shfl_xor(val, 1);
                    const float cs = cosp[ll * 64 + d];
                    const float sn = sinp[ll * 64 + d];
                    float res = val * cs + ((d & 1) ? other : -other) * sn;
                    res *= (wsel == 1) ? 0.125f : LOG2E;
                    __hip_bfloat16* dst = (wsel == 1) ? kr : qr;
                    dst[(size_t)((bb * 12 + nh) * 1024 + ll) * 64 + d] = __float2bfloat16(res);
                }
            }
        }
    }
}

// ---------------------------------------------------------------------------
// Kernel 2: FUSED attention + LEPE conv.
// blocks 0..1535  : flash attention (r14/r18 structure), writes aout
// blocks 1536..2303: depthwise 5x5 conv v_t -> lepeb.
// LDS via union; lepe image rows padded to 1032 elems (stride = 4 banks)
// so the 8 channel rows land on distinct banks -> conflict-free taps
// (r19's 33M extra conflicts throttled co-resident attn blocks).
// ---------------------------------------------------------------------------
union SMem {
    struct {
        __hip_bfloat16 K[64][LDS_PAD];
        __hip_bfloat16 V[64][LDS_PAD];
        __hip_bfloat16 P[4][16][LDS_PAD];
    } a;
    __hip_bfloat16 img[8][1032];
};

__global__ __launch_bounds__(256) void attn_lepe(
    const __hip_bfloat16* __restrict__ qr,
    const __hip_bfloat16* __restrict__ kr,
    const __hip_bfloat16* __restrict__ v_t,
    const float* __restrict__ mask,
    const float* __restrict__ lw,
    const float* __restrict__ lb,
    __hip_bfloat16* __restrict__ attn_out,
    __hip_bfloat16* __restrict__ lepeb)
{
    __shared__ __align__(16) SMem smem;

    const int blk = blockIdx.x;
    const int t = threadIdx.x;

    if (blk >= 1536) {
        // ----------------- LEPE path -----------------
        const int lbk = blk - 1536;
        const int b  = lbk / 96;
        const int cg = lbk % 96;
        const int c0 = cg * 8;

        for (int i = t; i < 2048; i += 256) {
            const int ci = i >> 8, l4 = (i & 255) << 2;
            const int c = c0 + ci, nh = c >> 6, d = c & 63;
            *(bf16x4*)&smem.img[ci][l4] =
                *(const bf16x4*)&v_t[(size_t)((b * 12 + nh) * 64 + d) * 1024 + l4];
        }
        __syncthreads();

        const int ci = t & 7, c = c0 + ci;
        float wt[25];
        #pragma unroll
        for (int k = 0; k < 25; ++k) wt[k] = lw[k * 768 + c];
        const float bias = lb[c];

        for (int l0 = t >> 3; l0 < 1024; l0 += 32) {
            const int h = l0 >> 5, w = l0 & 31;
            float s = bias;
            #pragma unroll
            for (int dy = 0; dy < 5; ++dy) {
                const int hy = h + dy - 2;
                if (hy < 0 || hy > 31) continue;
                #pragma unroll
                for (int dx = 0; dx < 5; ++dx) {
                    const int wx = w + dx - 2;
                    if (wx < 0 || wx > 31) continue;
                    s += bf2f(smem.img[ci][hy * 32 + wx]) * wt[dy * 5 + dx];
                }
            }
            lepeb[(size_t)(b * 1024 + l0) * 768 + c] = __float2bfloat16(s);
        }
        return;
    }

    // ----------------- attention path -----------------
    const int qt = blk & 15;        // 0..15
    const int bh = blk >> 4;        // 0..95
    const int b = bh / 12, nh = bh % 12;

    const int lane = t & 63, w = t >> 6;
    const int l15 = lane & 15, lhi = lane >> 4;
    const int qg = qt * 64 + w * 16 + l15;

    bf16x8 qf[2];   // q pre-scaled by log2(e)
    qf[0] = *(const bf16x8*)&qr[((size_t)bh * 1024 + qg) * 64 + lhi * 8];
    qf[1] = *(const bf16x8*)&qr[((size_t)bh * 1024 + qg) * 64 + 32 + lhi * 8];

    f32x4 o[4] = {};
    float l_run = 0.f;

    const int srow = t >> 3;
    const int scol = (t & 7) * 8;

    const float* mbase = mask + ((size_t)nh << 20) + (size_t)qg * 1024;

    bf16x8 kb0, kb1, vb0, vb1;
    float4 mv[4];
    {
        const size_t kbase = ((size_t)bh * 1024) * 64;
        kb0 = *(const bf16x8*)&kr[kbase + (size_t)srow * 64 + scol];
        kb1 = *(const bf16x8*)&kr[kbase + (size_t)(srow + 32) * 64 + scol];
        const size_t vbase = (size_t)bh * 64 * 1024;
        vb0 = *(const bf16x8*)&v_t[vbase + (size_t)srow * 1024 + scol];
        vb1 = *(const bf16x8*)&v_t[vbase + (size_t)(srow + 32) * 1024 + scol];
        #pragma unroll
        for (int n = 0; n < 4; ++n)
            mv[n] = *(const float4*)&mbase[n * 16 + lhi * 4];
    }

    for (int kt = 0; kt < 16; ++kt) {
        *(bf16x8*)&smem.a.K[srow][scol]       = kb0;
        *(bf16x8*)&smem.a.K[srow + 32][scol]  = kb1;
        *(bf16x8*)&smem.a.V[srow][scol]       = vb0;
        *(bf16x8*)&smem.a.V[srow + 32][scol]  = vb1;
        __syncthreads();

        float4 mvn[4];
        if (kt < 15) {
            const size_t kbase = ((size_t)bh * 1024 + (kt + 1) * 64) * 64;
            kb0 = *(const bf16x8*)&kr[kbase + (size_t)srow * 64 + scol];
            kb1 = *(const bf16x8*)&kr[kbase + (size_t)(srow + 32) * 64 + scol];
            const size_t vbase = (size_t)bh * 64 * 1024 + (kt + 1) * 64;
            vb0 = *(const bf16x8*)&v_t[vbase + (size_t)srow * 1024 + scol];
            vb1 = *(const bf16x8*)&v_t[vbase + (size_t)(srow + 32) * 1024 + scol];
            #pragma unroll
            for (int n = 0; n < 4; ++n)
                mvn[n] = *(const float4*)&mbase[(kt + 1) * 64 + n * 16 + lhi * 4];
        }

        f32x4 s[4] = {};
        __builtin_amdgcn_s_setprio(1);
        #pragma unroll
        for (int n = 0; n < 4; ++n) {
            const bf16x8 kf0 = *(const bf16x8*)&smem.a.K[n * 16 + l15][lhi * 8];
            const bf16x8 kf1 = *(const bf16x8*)&smem.a.K[n * 16 + l15][32 + lhi * 8];
            s[n] = __builtin_amdgcn_mfma_f32_16x16x32_bf16(kf0, qf[0], s[n], 0, 0, 0);
            s[n] = __builtin_amdgcn_mfma_f32_16x16x32_bf16(kf1, qf[1], s[n], 0, 0, 0);
        }
        __builtin_amdgcn_s_setprio(0);

        #pragma unroll
        for (int n = 0; n < 4; ++n) {
            bf16x4 pk;
            #pragma unroll
            for (int r = 0; r < 4; ++r) {
                const float p = exp2f(fmaf(((const float*)&mv[n])[r], LOG2E, s[n][r]));
                l_run += p;
                ((__hip_bfloat16*)&pk)[r] = __float2bfloat16(p);
            }
            *(bf16x4*)&smem.a.P[w][l15][n * 16 + lhi * 4] = pk;
        }
        asm volatile("s_waitcnt lgkmcnt(0)" ::: "memory");
        __builtin_amdgcn_sched_barrier(0);

        __builtin_amdgcn_s_setprio(1);
        #pragma unroll
        for (int ks = 0; ks < 2; ++ks) {
            const bf16x8 pf = *(const bf16x8*)&smem.a.P[w][l15][ks * 32 + lhi * 8];
            #pragma unroll
            for (int m = 0; m < 4; ++m) {
                const bf16x8 vf = *(const bf16x8*)&smem.a.V[m * 16 + l15][ks * 32 + lhi * 8];
                o[m] = __builtin_amdgcn_mfma_f32_16x16x32_bf16(vf, pf, o[m], 0, 0, 0);
            }
        }
        __builtin_amdgcn_s_setprio(0);
        __syncthreads();

        #pragma unroll
        for (int n = 0; n < 4; ++n) mv[n] = mvn[n];
    }

    l_run += __shfl_xor(l_run, 16);
    l_run += __shfl_xor(l_run, 32);

    const float rl = 1.f / l_run;
    #pragma unroll
    for (int m = 0; m < 4; ++m) {
        bf16x4 pk;
        #pragma unroll
        for (int r = 0; r < 4; ++r)
            ((__hip_bfloat16*)&pk)[r] = __float2bfloat16(o[m][r] * rl);
        *(bf16x4*)&attn_out[((size_t)b * 1024 + qg) * 768 + nh * 64 + m * 16 + lhi * 4] = pk;
    }
}

// ---------------------------------------------------------------------------
// Kernel 3: output projection: out = (aout + lepeb) @ wo^T + bo.
// 512 threads / 8 waves, wave tile 32x64. A reg-staged with fused add
// (prefetched one K-step ahead); B via gload_lds.
// ---------------------------------------------------------------------------
__global__ __launch_bounds__(512) void proj_gemm(
    const __hip_bfloat16* __restrict__ aout,
    const __hip_bfloat16* __restrict__ lepeb,
    const __hip_bfloat16* __restrict__ wb,
    const float* __restrict__ bo,
    float* __restrict__ out)
{
    __shared__ __align__(16) __hip_bfloat16 Alds[128 * 64];
    __shared__ __align__(16) __hip_bfloat16 Blds[128 * 64];

    const int t    = threadIdx.x;
    const int lane = t & 63;
    const int w    = t >> 6;
    const int wm   = w >> 1, wn = w & 1;
    const int l15  = lane & 15, lhi = lane >> 4;

    const int rm = blockIdx.x, cn = blockIdx.y;
    const __hip_bfloat16* wgt = wb + (size_t)3 * 589824;

    const int srow = w * 16 + (lane >> 3);
    const int scol = (lane & 7) * 8;
    const size_t aoff0 = (size_t)(rm * 128 + srow) * 768 + scol;
    const __hip_bfloat16* bsrc = wgt + (size_t)(cn * 128 + srow) * 768 + scol;
    const int lds_off = srow * 64 + scol;

    f32x4 acc[2][4] = {};

    bf16x8 ar[2];
    #pragma unroll
    for (int j = 0; j < 2; ++j) {
        const size_t off = aoff0 + (size_t)j * 8 * 768;
        const bf16x8 a1 = *(const bf16x8*)&aout[off];
        const bf16x8 a2 = *(const bf16x8*)&lepeb[off];
        #pragma unroll
        for (int e = 0; e < 8; ++e)
            ((__hip_bfloat16*)&ar[j])[e] = __float2bfloat16(
                bf2f(((const __hip_bfloat16*)&a1)[e]) + bf2f(((const __hip_bfloat16*)&a2)[e]));
    }

    for (int k0 = 0; k0 < 768; k0 += 64) {
        __syncthreads();
        #pragma unroll
        for (int j = 0; j < 2; ++j)
            *(bf16x8*)&Alds[lds_off + j * 8 * 64] = ar[j];
        #pragma unroll
        for (int j = 0; j < 2; ++j)
            gload_lds16(bsrc + (size_t)j * 8 * 768 + k0, Blds + (w * 2 + j) * 512);
        __syncthreads();

        if (k0 + 64 < 768) {
            #pragma unroll
            for (int j = 0; j < 2; ++j) {
                const size_t off = aoff0 + (size_t)j * 8 * 768 + k0 + 64;
                const bf16x8 a1 = *(const bf16x8*)&aout[off];
                const bf16x8 a2 = *(const bf16x8*)&lepeb[off];
                #pragma unroll
                for (int e = 0; e < 8; ++e)
                    ((__hip_bfloat16*)&ar[j])[e] = __float2bfloat16(
                        bf2f(((const __hip_bfloat16*)&a1)[e]) + bf2f(((const __hip_bfloat16*)&a2)[e]));
            }
        }

        #pragma unroll
        for (int kk = 0; kk < 2; ++kk) {
            bf16x8 af[2], bfr[4];
            #pragma unroll
            for (int m = 0; m < 2; ++m)
                af[m] = *(const bf16x8*)&Alds[(wm * 32 + m * 16 + l15) * 64 + kk * 32 + lhi * 8];
            #pragma unroll
            for (int n = 0; n < 4; ++n)
                bfr[n] = *(const bf16x8*)&Blds[(wn * 64 + n * 16 + l15) * 64 + kk * 32 + lhi * 8];
            #pragma unroll
            for (int m = 0; m < 2; ++m)
                #pragma unroll
                for (int n = 0; n < 4; ++n)
                    acc[m][n] = __builtin_amdgcn_mfma_f32_16x16x32_bf16(af[m], bfr[n], acc[m][n], 0, 0, 0);
        }
    }

    #pragma unroll
    for (int m = 0; m < 2; ++m)
        #pragma unroll
        for (int n = 0; n < 4; ++n) {
            const int gcol = cn * 128 + wn * 64 + n * 16 + l15;
            const float bcol = bo[gcol];
            #pragma unroll
            for (int r = 0; r < 4; ++r) {
                const int grow = rm * 128 + wm * 32 + m * 16 + lhi * 4 + r;
                out[(size_t)grow * 768 + gcol] = acc[m][n][r] + bcol;
            }
        }
}

// ---------------------------------------------------------------------------
extern "C" void kernel_launch(void* const* d_in, const int* in_sizes, int n_in,
                              void* d_out, int out_size, void* d_ws, size_t ws_size,
                              hipStream_t stream) {
    const float* x    = (const float*)d_in[0];
    const float* sinp = (const float*)d_in[1];
    const float* cosp = (const float*)d_in[2];
    const float* mask = (const float*)d_in[3];
    const float* wq   = (const float*)d_in[4];
    const float* bq   = (const float*)d_in[5];
    const float* wk   = (const float*)d_in[6];
    const float* bk   = (const float*)d_in[7];
    const float* wvw  = (const float*)d_in[8];
    const float* bv   = (const float*)d_in[9];
    const float* lw   = (const float*)d_in[10];
    const float* lb   = (const float*)d_in[11];
    const float* wo   = (const float*)d_in[12];
    const float* bo   = (const float*)d_in[13];
    float* out = (float*)d_out;

    char* ws = (char*)d_ws;
    const size_t SZ = (size_t)8192 * 768 * 2;    // 12.58 MB per bf16 buffer
    __hip_bfloat16* qr    = (__hip_bfloat16*)(ws);
    __hip_bfloat16* kr    = (__hip_bfloat16*)(ws + SZ);
    __hip_bfloat16* v_t   = (__hip_bfloat16*)(ws + 2 * SZ);
    __hip_bfloat16* xb    = (__hip_bfloat16*)(ws + 3 * SZ);
    __hip_bfloat16* wb    = (__hip_bfloat16*)(ws + 4 * SZ);             // 4.5 MB
    __hip_bfloat16* lepeb = (__hip_bfloat16*)(ws + 4 * SZ + 4718592);   // 12.58 MB
    __hip_bfloat16* aout  = xb;   // xb dead after qkv_gemm

    cvt_in<<<dim3(4224), 256, 0, stream>>>(x, wq, wk, wvw, wo, xb, wb);
    qkv_gemm<<<dim3(64, 18), 512, 0, stream>>>(xb, wb, bq, bk, bv,
                                               sinp, cosp, qr, kr, v_t);
    attn_lepe<<<dim3(2304), 256, 0, stream>>>(qr, kr, v_t, mask, lw, lb, aout, lepeb);
    proj_gemm<<<dim3(64, 6), 512, 0, stream>>>(aout, lepeb, wb, bo, out);
}

// Round 21
// 182.578 us; speedup vs baseline: 1.3566x; 1.1201x over previous
//
#include <hip/hip_runtime.h>
#include <hip/hip_bf16.h>

typedef __attribute__((ext_vector_type(8))) short bf16x8;
typedef __attribute__((ext_vector_type(4))) short bf16x4;
typedef __attribute__((ext_vector_type(4))) float f32x4;

#define LDS_PAD 72
#define LOG2E 1.44269504088896f

static __device__ __forceinline__ float bf2f(__hip_bfloat16 v) { return __bfloat162float(v); }

// load 8 consecutive f32, round to bf16x8
static __device__ __forceinline__ bf16x8 ld8f_bf16(const float* __restrict__ p) {
    const float4 a = *(const float4*)p;
    const float4 b = *(const float4*)(p + 4);
    bf16x8 r;
    __hip_bfloat16* h = (__hip_bfloat16*)&r;
    h[0] = __float2bfloat16(a.x); h[1] = __float2bfloat16(a.y);
    h[2] = __float2bfloat16(a.z); h[3] = __float2bfloat16(a.w);
    h[4] = __float2bfloat16(b.x); h[5] = __float2bfloat16(b.y);
    h[6] = __float2bfloat16(b.z); h[7] = __float2bfloat16(b.w);
    return r;
}

// async global->LDS, 16B per lane; lds base must be wave-uniform
static __device__ __forceinline__ void gload_lds16(const __hip_bfloat16* g, __hip_bfloat16* l) {
    __builtin_amdgcn_global_load_lds(
        (const __attribute__((address_space(1))) void*)g,
        (__attribute__((address_space(3))) void*)l, 16, 0, 0);
}

// ---------------------------------------------------------------------------
// Kernel 0: merged f32 -> bf16 conversion (x + the 4 weight matrices).
// ---------------------------------------------------------------------------
__global__ __launch_bounds__(256) void cvt_in(
    const float* __restrict__ x,
    const float* __restrict__ w0, const float* __restrict__ w1,
    const float* __restrict__ w2, const float* __restrict__ w3,
    __hip_bfloat16* __restrict__ xb, __hip_bfloat16* __restrict__ wb)
{
    const int blk = blockIdx.x;
    if (blk < 3072) {
        const int i = (blk * 256 + threadIdx.x) * 8;
        *(bf16x8*)(xb + i) = ld8f_bf16(x + i);
    } else {
        const float* srcs[4] = {w0, w1, w2, w3};
        const int wblk = blk - 3072;
        const int b = wblk / 288;
        const int i = ((wblk % 288) * 256 + threadIdx.x) * 8;
        *(bf16x8*)(wb + (size_t)b * 589824 + i) = ld8f_bf16(srcs[b] + i);
    }
}

// ---------------------------------------------------------------------------
// Kernel 1: fused QKV projection, 512 threads / 8 waves (wave tile 32x64).
// BK=32, 3-deep buffered gload_lds with counted vmcnt(2) + raw s_barrier.
// Outputs:
//   qr, kr : [((b*12+nh)*1024 + l)*64 + d]   (q pre-scaled by log2e)
//   v_t    : [((b*12+nh)*64 + d)*1024 + l]
// ---------------------------------------------------------------------------
__global__ __launch_bounds__(512) void qkv_gemm(
    const __hip_bfloat16* __restrict__ xb,
    const __hip_bfloat16* __restrict__ wb,
    const float* __restrict__ bq, const float* __restrict__ bk,
    const float* __restrict__ bv,
    const float* __restrict__ sinp, const float* __restrict__ cosp,
    __hip_bfloat16* __restrict__ qr, __hip_bfloat16* __restrict__ kr,
    __hip_bfloat16* __restrict__ v_t)
{
    __shared__ __align__(16) __hip_bfloat16 Alds[3][128 * 32];
    __shared__ __align__(16) __hip_bfloat16 Blds[3][128 * 32];

    const int t    = threadIdx.x;
    const int lane = t & 63;
    const int w    = t >> 6;           // 0..7
    const int wm   = w >> 1, wn = w & 1;
    const int l15  = lane & 15, lhi = lane >> 4;

    const int rm   = blockIdx.x;       // row tile 0..63
    const int cy   = blockIdx.y;       // 0..17
    const int wsel = cy / 6;           // 0=q,1=k,2=v
    const int cn   = cy % 6;

    const __hip_bfloat16* wgt = wb + (size_t)wsel * 589824;
    const float* bias = (wsel == 0) ? bq : (wsel == 1) ? bk : bv;

    const __hip_bfloat16* asrc = xb  + (size_t)(rm * 128 + w * 16 + (lane >> 2)) * 768 + (lane & 3) * 8;
    const __hip_bfloat16* bsrc = wgt + (size_t)(cn * 128 + w * 16 + (lane >> 2)) * 768 + (lane & 3) * 8;

    f32x4 acc[2][4] = {};

    __hip_bfloat16 *pa0 = Alds[0], *pa1 = Alds[1], *pa2 = Alds[2];
    __hip_bfloat16 *pb0 = Blds[0], *pb1 = Blds[1], *pb2 = Blds[2];

    gload_lds16(asrc,      pa0 + w * 512);
    gload_lds16(bsrc,      pb0 + w * 512);
    gload_lds16(asrc + 32, pa1 + w * 512);
    gload_lds16(bsrc + 32, pb1 + w * 512);

    for (int i = 0; i < 24; ++i) {
        if (i < 23) asm volatile("s_waitcnt vmcnt(2)" ::: "memory");
        else        asm volatile("s_waitcnt vmcnt(0)" ::: "memory");
        __builtin_amdgcn_s_barrier();

        if (i + 2 < 24) {
            gload_lds16(asrc + (i + 2) * 32, pa2 + w * 512);
            gload_lds16(bsrc + (i + 2) * 32, pb2 + w * 512);
        }

        {
            bf16x8 af[2], bfr[4];
            #pragma unroll
            for (int m = 0; m < 2; ++m)
                af[m] = *(const bf16x8*)&pa0[(wm * 32 + m * 16 + l15) * 32 + lhi * 8];
            #pragma unroll
            for (int n = 0; n < 4; ++n)
                bfr[n] = *(const bf16x8*)&pb0[(wn * 64 + n * 16 + l15) * 32 + lhi * 8];
            #pragma unroll
            for (int m = 0; m < 2; ++m)
                #pragma unroll
                for (int n = 0; n < 4; ++n)
                    acc[m][n] = __builtin_amdgcn_mfma_f32_16x16x32_bf16(af[m], bfr[n], acc[m][n], 0, 0, 0);
        }

        __hip_bfloat16* ta = pa0; pa0 = pa1; pa1 = pa2; pa2 = ta;
        __hip_bfloat16* tb = pb0; pb0 = pb1; pb1 = pb2; pb2 = tb;
    }

    #pragma unroll
    for (int m = 0; m < 2; ++m) {
        #pragma unroll
        for (int n = 0; n < 4; ++n) {
            const int gcol = cn * 128 + wn * 64 + n * 16 + l15;   // 0..767
            const float bcol = bias[gcol];
            const int nh = gcol >> 6, d = gcol & 63;
            const int grow0 = rm * 128 + wm * 32 + m * 16 + lhi * 4;
            const int bb = grow0 >> 10, ll0 = grow0 & 1023;
            if (wsel == 2) {
                bf16x4 pk;
                #pragma unroll
                for (int r = 0; r < 4; ++r)
                    ((__hip_bfloat16*)&pk)[r] = __float2bfloat16(acc[m][n][r] + bcol);
                *(bf16x4*)&v_t[(size_t)((bb * 12 + nh) * 64 + d) * 1024 + ll0] = pk;
            } else {
                #pragma unroll
                for (int r = 0; r < 4; ++r) {
                    const int ll = ll0 + r;
                    const float val = acc[m][n][r] + bcol;
                    const float other = __shfl_xor(val, 1);
                    const float cs = cosp[ll * 64 + d];
                    const float sn = sinp[ll * 64 + d];
                    float res = val * cs + ((d & 1) ? other : -other) * sn;
                    res *= (wsel == 1) ? 0.125f : LOG2E;
                    __hip_bfloat16* dst = (wsel == 1) ? kr : qr;
                    dst[(size_t)((bb * 12 + nh) * 1024 + ll) * 64 + d] = __float2bfloat16(res);
                }
            }
        }
    }
}

// ---------------------------------------------------------------------------
// Kernel 2: FUSED attention + LEPE conv.
// blocks 0..1535  : flash attention (r14/r18 structure), writes aout
// blocks 1536..2303: depthwise 5x5 conv v_t -> lepeb (bank-padded rows,
//                    VECTORIZED consume: <=60 ds_read_b128/thread instead of
//                    800 scalar ds_read_u16 -> far less issue pressure on
//                    co-resident attn blocks).
// ---------------------------------------------------------------------------
union SMem {
    struct {
        __hip_bfloat16 K[64][LDS_PAD];
        __hip_bfloat16 V[64][LDS_PAD];
        __hip_bfloat16 P[4][16][LDS_PAD];
    } a;
    __hip_bfloat16 img[8][1032];
};

__global__ __launch_bounds__(256) void attn_lepe(
    const __hip_bfloat16* __restrict__ qr,
    const __hip_bfloat16* __restrict__ kr,
    const __hip_bfloat16* __restrict__ v_t,
    const float* __restrict__ mask,
    const float* __restrict__ lw,
    const float* __restrict__ lb,
    __hip_bfloat16* __restrict__ attn_out,
    __hip_bfloat16* __restrict__ lepeb)
{
    __shared__ __align__(16) SMem smem;

    const int blk = blockIdx.x;
    const int t = threadIdx.x;

    if (blk >= 1536) {
        // ----------------- LEPE path -----------------
        const int lbk = blk - 1536;
        const int b  = lbk / 96;
        const int cg = lbk % 96;
        const int c0 = cg * 8;

        for (int i = t; i < 2048; i += 256) {
            const int ci = i >> 8, l4 = (i & 255) << 2;
            const int c = c0 + ci, nh = c >> 6, d = c & 63;
            *(bf16x4*)&smem.img[ci][l4] =
                *(const bf16x4*)&v_t[(size_t)((b * 12 + nh) * 64 + d) * 1024 + l4];
        }
        __syncthreads();

        const int ci = t & 7, c = c0 + ci;
        const int h  = t >> 3;            // this thread's output row (0..31)
        float wt[25];
        #pragma unroll
        for (int k = 0; k < 25; ++k) wt[k] = lw[k * 768 + c];
        const float bias = lb[c];

        #pragma unroll
        for (int wb = 0; wb < 4; ++wb) {   // 8 outputs per w-block
            float acc8[8];
            #pragma unroll
            for (int j = 0; j < 8; ++j) acc8[j] = bias;

            #pragma unroll
            for (int dy = 0; dy < 5; ++dy) {
                const int hy = h + dy - 2;
                if (hy < 0 || hy > 31) continue;          // runtime row clamp
                float v[12];                               // cols wb*8-2 .. wb*8+9
                #pragma unroll
                for (int cc = 0; cc < 3; ++cc) {
                    const int cch = wb - 1 + cc;           // chunk index
                    if (cch < 0 || cch > 3) continue;      // compile-time
                    const bf16x8 chunk = *(const bf16x8*)&smem.img[ci][hy * 32 + cch * 8];
                    #pragma unroll
                    for (int e = 0; e < 8; ++e) {
                        const int j = cch * 8 + e - (wb * 8 - 2);
                        if (j >= 0 && j < 12)
                            v[j] = bf2f(((const __hip_bfloat16*)&chunk)[e]);
                    }
                }
                #pragma unroll
                for (int j = 0; j < 12; ++j) {             // zero taps outside image row
                    const int x = wb * 8 + j - 2;
                    if (x < 0 || x > 31) v[j] = 0.f;
                }
                #pragma unroll
                for (int jw = 0; jw < 8; ++jw)
                    #pragma unroll
                    for (int dx = 0; dx < 5; ++dx)
                        acc8[jw] = fmaf(v[jw + dx], wt[dy * 5 + dx], acc8[jw]);
            }

            #pragma unroll
            for (int jw = 0; jw < 8; ++jw)
                lepeb[(size_t)(b * 1024 + h * 32 + wb * 8 + jw) * 768 + c] =
                    __float2bfloat16(acc8[jw]);
        }
        return;
    }

    // ----------------- attention path -----------------
    const int qt = blk & 15;        // 0..15
    const int bh = blk >> 4;        // 0..95
    const int b = bh / 12, nh = bh % 12;

    const int lane = t & 63, w = t >> 6;
    const int l15 = lane & 15, lhi = lane >> 4;
    const int qg = qt * 64 + w * 16 + l15;

    bf16x8 qf[2];   // q pre-scaled by log2(e)
    qf[0] = *(const bf16x8*)&qr[((size_t)bh * 1024 + qg) * 64 + lhi * 8];
    qf[1] = *(const bf16x8*)&qr[((size_t)bh * 1024 + qg) * 64 + 32 + lhi * 8];

    f32x4 o[4] = {};
    float l_run = 0.f;

    const int srow = t >> 3;
    const int scol = (t & 7) * 8;

    const float* mbase = mask + ((size_t)nh << 20) + (size_t)qg * 1024;

    bf16x8 kb0, kb1, vb0, vb1;
    float4 mv[4];
    {
        const size_t kbase = ((size_t)bh * 1024) * 64;
        kb0 = *(const bf16x8*)&kr[kbase + (size_t)srow * 64 + scol];
        kb1 = *(const bf16x8*)&kr[kbase + (size_t)(srow + 32) * 64 + scol];
        const size_t vbase = (size_t)bh * 64 * 1024;
        vb0 = *(const bf16x8*)&v_t[vbase + (size_t)srow * 1024 + scol];
        vb1 = *(const bf16x8*)&v_t[vbase + (size_t)(srow + 32) * 1024 + scol];
        #pragma unroll
        for (int n = 0; n < 4; ++n)
            mv[n] = *(const float4*)&mbase[n * 16 + lhi * 4];
    }

    for (int kt = 0; kt < 16; ++kt) {
        *(bf16x8*)&smem.a.K[srow][scol]       = kb0;
        *(bf16x8*)&smem.a.K[srow + 32][scol]  = kb1;
        *(bf16x8*)&smem.a.V[srow][scol]       = vb0;
        *(bf16x8*)&smem.a.V[srow + 32][scol]  = vb1;
        __syncthreads();

        float4 mvn[4];
        if (kt < 15) {
            const size_t kbase = ((size_t)bh * 1024 + (kt + 1) * 64) * 64;
            kb0 = *(const bf16x8*)&kr[kbase + (size_t)srow * 64 + scol];
            kb1 = *(const bf16x8*)&kr[kbase + (size_t)(srow + 32) * 64 + scol];
            const size_t vbase = (size_t)bh * 64 * 1024 + (kt + 1) * 64;
            vb0 = *(const bf16x8*)&v_t[vbase + (size_t)srow * 1024 + scol];
            vb1 = *(const bf16x8*)&v_t[vbase + (size_t)(srow + 32) * 1024 + scol];
            #pragma unroll
            for (int n = 0; n < 4; ++n)
                mvn[n] = *(const float4*)&mbase[(kt + 1) * 64 + n * 16 + lhi * 4];
        }

        f32x4 s[4] = {};
        __builtin_amdgcn_s_setprio(1);
        #pragma unroll
        for (int n = 0; n < 4; ++n) {
            const bf16x8 kf0 = *(const bf16x8*)&smem.a.K[n * 16 + l15][lhi * 8];
            const bf16x8 kf1 = *(const bf16x8*)&smem.a.K[n * 16 + l15][32 + lhi * 8];
            s[n] = __builtin_amdgcn_mfma_f32_16x16x32_bf16(kf0, qf[0], s[n], 0, 0, 0);
            s[n] = __builtin_amdgcn_mfma_f32_16x16x32_bf16(kf1, qf[1], s[n], 0, 0, 0);
        }
        __builtin_amdgcn_s_setprio(0);

        #pragma unroll
        for (int n = 0; n < 4; ++n) {
            bf16x4 pk;
            #pragma unroll
            for (int r = 0; r < 4; ++r) {
                const float p = exp2f(fmaf(((const float*)&mv[n])[r], LOG2E, s[n][r]));
                l_run += p;
                ((__hip_bfloat16*)&pk)[r] = __float2bfloat16(p);
            }
            *(bf16x4*)&smem.a.P[w][l15][n * 16 + lhi * 4] = pk;
        }
        asm volatile("s_waitcnt lgkmcnt(0)" ::: "memory");
        __builtin_amdgcn_sched_barrier(0);

        __builtin_amdgcn_s_setprio(1);
        #pragma unroll
        for (int ks = 0; ks < 2; ++ks) {
            const bf16x8 pf = *(const bf16x8*)&smem.a.P[w][l15][ks * 32 + lhi * 8];
            #pragma unroll
            for (int m = 0; m < 4; ++m) {
                const bf16x8 vf = *(const bf16x8*)&smem.a.V[m * 16 + l15][ks * 32 + lhi * 8];
                o[m] = __builtin_amdgcn_mfma_f32_16x16x32_bf16(vf, pf, o[m], 0, 0, 0);
            }
        }
        __builtin_amdgcn_s_setprio(0);
        __syncthreads();

        #pragma unroll
        for (int n = 0; n < 4; ++n) mv[n] = mvn[n];
    }

    l_run += __shfl_xor(l_run, 16);
    l_run += __shfl_xor(l_run, 32);

    const float rl = 1.f / l_run;
    #pragma unroll
    for (int m = 0; m < 4; ++m) {
        bf16x4 pk;
        #pragma unroll
        for (int r = 0; r < 4; ++r)
            ((__hip_bfloat16*)&pk)[r] = __float2bfloat16(o[m][r] * rl);
        *(bf16x4*)&attn_out[((size_t)b * 1024 + qg) * 768 + nh * 64 + m * 16 + lhi * 4] = pk;
    }
}

// ---------------------------------------------------------------------------
// Kernel 3: output projection: out = (aout + lepeb) @ wo^T + bo.
// 512 threads / 8 waves, wave tile 32x64. A reg-staged with fused add
// (prefetched one K-step ahead); B via gload_lds.
// ---------------------------------------------------------------------------
__global__ __launch_bounds__(512) void proj_gemm(
    const __hip_bfloat16* __restrict__ aout,
    const __hip_bfloat16* __restrict__ lepeb,
    const __hip_bfloat16* __restrict__ wb,
    const float* __restrict__ bo,
    float* __restrict__ out)
{
    __shared__ __align__(16) __hip_bfloat16 Alds[128 * 64];
    __shared__ __align__(16) __hip_bfloat16 Blds[128 * 64];

    const int t    = threadIdx.x;
    const int lane = t & 63;
    const int w    = t >> 6;
    const int wm   = w >> 1, wn = w & 1;
    const int l15  = lane & 15, lhi = lane >> 4;

    const int rm = blockIdx.x, cn = blockIdx.y;
    const __hip_bfloat16* wgt = wb + (size_t)3 * 589824;

    const int srow = w * 16 + (lane >> 3);
    const int scol = (lane & 7) * 8;
    const size_t aoff0 = (size_t)(rm * 128 + srow) * 768 + scol;
    const __hip_bfloat16* bsrc = wgt + (size_t)(cn * 128 + srow) * 768 + scol;
    const int lds_off = srow * 64 + scol;

    f32x4 acc[2][4] = {};

    bf16x8 ar[2];
    #pragma unroll
    for (int j = 0; j < 2; ++j) {
        const size_t off = aoff0 + (size_t)j * 8 * 768;
        const bf16x8 a1 = *(const bf16x8*)&aout[off];
        const bf16x8 a2 = *(const bf16x8*)&lepeb[off];
        #pragma unroll
        for (int e = 0; e < 8; ++e)
            ((__hip_bfloat16*)&ar[j])[e] = __float2bfloat16(
                bf2f(((const __hip_bfloat16*)&a1)[e]) + bf2f(((const __hip_bfloat16*)&a2)[e]));
    }

    for (int k0 = 0; k0 < 768; k0 += 64) {
        __syncthreads();
        #pragma unroll
        for (int j = 0; j < 2; ++j)
            *(bf16x8*)&Alds[lds_off + j * 8 * 64] = ar[j];
        #pragma unroll
        for (int j = 0; j < 2; ++j)
            gload_lds16(bsrc + (size_t)j * 8 * 768 + k0, Blds + (w * 2 + j) * 512);
        __syncthreads();

        if (k0 + 64 < 768) {
            #pragma unroll
            for (int j = 0; j < 2; ++j) {
                const size_t off = aoff0 + (size_t)j * 8 * 768 + k0 + 64;
                const bf16x8 a1 = *(const bf16x8*)&aout[off];
                const bf16x8 a2 = *(const bf16x8*)&lepeb[off];
                #pragma unroll
                for (int e = 0; e < 8; ++e)
                    ((__hip_bfloat16*)&ar[j])[e] = __float2bfloat16(
                        bf2f(((const __hip_bfloat16*)&a1)[e]) + bf2f(((const __hip_bfloat16*)&a2)[e]));
            }
        }

        #pragma unroll
        for (int kk = 0; kk < 2; ++kk) {
            bf16x8 af[2], bfr[4];
            #pragma unroll
            for (int m = 0; m < 2; ++m)
                af[m] = *(const bf16x8*)&Alds[(wm * 32 + m * 16 + l15) * 64 + kk * 32 + lhi * 8];
            #pragma unroll
            for (int n = 0; n < 4; ++n)
                bfr[n] = *(const bf16x8*)&Blds[(wn * 64 + n * 16 + l15) * 64 + kk * 32 + lhi * 8];
            #pragma unroll
            for (int m = 0; m < 2; ++m)
                #pragma unroll
                for (int n = 0; n < 4; ++n)
                    acc[m][n] = __builtin_amdgcn_mfma_f32_16x16x32_bf16(af[m], bfr[n], acc[m][n], 0, 0, 0);
        }
    }

    #pragma unroll
    for (int m = 0; m < 2; ++m)
        #pragma unroll
        for (int n = 0; n < 4; ++n) {
            const int gcol = cn * 128 + wn * 64 + n * 16 + l15;
            const float bcol = bo[gcol];
            #pragma unroll
            for (int r = 0; r < 4; ++r) {
                const int grow = rm * 128 + wm * 32 + m * 16 + lhi * 4 + r;
                out[(size_t)grow * 768 + gcol] = acc[m][n][r] + bcol;
            }
        }
}

// ---------------------------------------------------------------------------
extern "C" void kernel_launch(void* const* d_in, const int* in_sizes, int n_in,
                              void* d_out, int out_size, void* d_ws, size_t ws_size,
                              hipStream_t stream) {
    const float* x    = (const float*)d_in[0];
    const float* sinp = (const float*)d_in[1];
    const float* cosp = (const float*)d_in[2];
    const float* mask = (const float*)d_in[3];
    const float* wq   = (const float*)d_in[4];
    const float* bq   = (const float*)d_in[5];
    const float* wk   = (const float*)d_in[6];
    const float* bk   = (const float*)d_in[7];
    const float* wvw  = (const float*)d_in[8];
    const float* bv   = (const float*)d_in[9];
    const float* lw   = (const float*)d_in[10];
    const float* lb   = (const float*)d_in[11];
    const float* wo   = (const float*)d_in[12];
    const float* bo   = (const float*)d_in[13];
    float* out = (float*)d_out;

    char* ws = (char*)d_ws;
    const size_t SZ = (size_t)8192 * 768 * 2;    // 12.58 MB per bf16 buffer
    __hip_bfloat16* qr    = (__hip_bfloat16*)(ws);
    __hip_bfloat16* kr    = (__hip_bfloat16*)(ws + SZ);
    __hip_bfloat16* v_t   = (__hip_bfloat16*)(ws + 2 * SZ);
    __hip_bfloat16* xb    = (__hip_bfloat16*)(ws + 3 * SZ);
    __hip_bfloat16* wb    = (__hip_bfloat16*)(ws + 4 * SZ);             // 4.5 MB
    __hip_bfloat16* lepeb = (__hip_bfloat16*)(ws + 4 * SZ + 4718592);   // 12.58 MB
    __hip_bfloat16* aout  = xb;   // xb dead after qkv_gemm

    cvt_in<<<dim3(4224), 256, 0, stream>>>(x, wq, wk, wvw, wo, xb, wb);
    qkv_gemm<<<dim3(64, 18), 512, 0, stream>>>(xb, wb, bq, bk, bv,
                                               sinp, cosp, qr, kr, v_t);
    attn_lepe<<<dim3(2304), 256, 0, stream>>>(qr, kr, v_t, mask, lw, lb, aout, lepeb);
    proj_gemm<<<dim3(64, 6), 512, 0, stream>>>(aout, lepeb, wb, bo, out);
}

// Round 22
// 167.207 us; speedup vs baseline: 1.4813x; 1.0919x over previous
//
#include <hip/hip_runtime.h>
#include <hip/hip_bf16.h>

typedef __attribute__((ext_vector_type(8))) short bf16x8;
typedef __attribute__((ext_vector_type(4))) short bf16x4;
typedef __attribute__((ext_vector_type(4))) float f32x4;

#define LDS_PAD 72
#define LOG2E 1.44269504088896f

static __device__ __forceinline__ float bf2f(__hip_bfloat16 v) { return __bfloat162float(v); }

// load 8 consecutive f32, round to bf16x8
static __device__ __forceinline__ bf16x8 ld8f_bf16(const float* __restrict__ p) {
    const float4 a = *(const float4*)p;
    const float4 b = *(const float4*)(p + 4);
    bf16x8 r;
    __hip_bfloat16* h = (__hip_bfloat16*)&r;
    h[0] = __float2bfloat16(a.x); h[1] = __float2bfloat16(a.y);
    h[2] = __float2bfloat16(a.z); h[3] = __float2bfloat16(a.w);
    h[4] = __float2bfloat16(b.x); h[5] = __float2bfloat16(b.y);
    h[6] = __float2bfloat16(b.z); h[7] = __float2bfloat16(b.w);
    return r;
}

// async global->LDS, 16B per lane; lds base must be wave-uniform
static __device__ __forceinline__ void gload_lds16(const __hip_bfloat16* g, __hip_bfloat16* l) {
    __builtin_amdgcn_global_load_lds(
        (const __attribute__((address_space(1))) void*)g,
        (__attribute__((address_space(3))) void*)l, 16, 0, 0);
}

// ---------------------------------------------------------------------------
// Kernel 0: merged f32 -> bf16 conversion (x + the 4 weight matrices).
// ---------------------------------------------------------------------------
__global__ __launch_bounds__(256) void cvt_in(
    const float* __restrict__ x,
    const float* __restrict__ w0, const float* __restrict__ w1,
    const float* __restrict__ w2, const float* __restrict__ w3,
    __hip_bfloat16* __restrict__ xb, __hip_bfloat16* __restrict__ wb)
{
    const int blk = blockIdx.x;
    if (blk < 3072) {
        const int i = (blk * 256 + threadIdx.x) * 8;
        *(bf16x8*)(xb + i) = ld8f_bf16(x + i);
    } else {
        const float* srcs[4] = {w0, w1, w2, w3};
        const int wblk = blk - 3072;
        const int b = wblk / 288;
        const int i = ((wblk % 288) * 256 + threadIdx.x) * 8;
        *(bf16x8*)(wb + (size_t)b * 589824 + i) = ld8f_bf16(srcs[b] + i);
    }
}

// ---------------------------------------------------------------------------
// Kernel 1: fused QKV projection, 512 threads / 8 waves (wave tile 32x64).
// BK=32, 3-deep buffered gload_lds with counted vmcnt(2) + raw s_barrier.
// Outputs:
//   qr, kr : [((b*12+nh)*1024 + l)*64 + d]   (q pre-scaled by log2e)
//   v_t    : [((b*12+nh)*64 + d)*1024 + l]
// ---------------------------------------------------------------------------
__global__ __launch_bounds__(512) void qkv_gemm(
    const __hip_bfloat16* __restrict__ xb,
    const __hip_bfloat16* __restrict__ wb,
    const float* __restrict__ bq, const float* __restrict__ bk,
    const float* __restrict__ bv,
    const float* __restrict__ sinp, const float* __restrict__ cosp,
    __hip_bfloat16* __restrict__ qr, __hip_bfloat16* __restrict__ kr,
    __hip_bfloat16* __restrict__ v_t)
{
    __shared__ __align__(16) __hip_bfloat16 Alds[3][128 * 32];
    __shared__ __align__(16) __hip_bfloat16 Blds[3][128 * 32];

    const int t    = threadIdx.x;
    const int lane = t & 63;
    const int w    = t >> 6;           // 0..7
    const int wm   = w >> 1, wn = w & 1;
    const int l15  = lane & 15, lhi = lane >> 4;

    const int rm   = blockIdx.x;       // row tile 0..63
    const int cy   = blockIdx.y;       // 0..17
    const int wsel = cy / 6;           // 0=q,1=k,2=v
    const int cn   = cy % 6;

    const __hip_bfloat16* wgt = wb + (size_t)wsel * 589824;
    const float* bias = (wsel == 0) ? bq : (wsel == 1) ? bk : bv;

    const __hip_bfloat16* asrc = xb  + (size_t)(rm * 128 + w * 16 + (lane >> 2)) * 768 + (lane & 3) * 8;
    const __hip_bfloat16* bsrc = wgt + (size_t)(cn * 128 + w * 16 + (lane >> 2)) * 768 + (lane & 3) * 8;

    f32x4 acc[2][4] = {};

    __hip_bfloat16 *pa0 = Alds[0], *pa1 = Alds[1], *pa2 = Alds[2];
    __hip_bfloat16 *pb0 = Blds[0], *pb1 = Blds[1], *pb2 = Blds[2];

    gload_lds16(asrc,      pa0 + w * 512);
    gload_lds16(bsrc,      pb0 + w * 512);
    gload_lds16(asrc + 32, pa1 + w * 512);
    gload_lds16(bsrc + 32, pb1 + w * 512);

    for (int i = 0; i < 24; ++i) {
        if (i < 23) asm volatile("s_waitcnt vmcnt(2)" ::: "memory");
        else        asm volatile("s_waitcnt vmcnt(0)" ::: "memory");
        __builtin_amdgcn_s_barrier();

        if (i + 2 < 24) {
            gload_lds16(asrc + (i + 2) * 32, pa2 + w * 512);
            gload_lds16(bsrc + (i + 2) * 32, pb2 + w * 512);
        }

        {
            bf16x8 af[2], bfr[4];
            #pragma unroll
            for (int m = 0; m < 2; ++m)
                af[m] = *(const bf16x8*)&pa0[(wm * 32 + m * 16 + l15) * 32 + lhi * 8];
            #pragma unroll
            for (int n = 0; n < 4; ++n)
                bfr[n] = *(const bf16x8*)&pb0[(wn * 64 + n * 16 + l15) * 32 + lhi * 8];
            #pragma unroll
            for (int m = 0; m < 2; ++m)
                #pragma unroll
                for (int n = 0; n < 4; ++n)
                    acc[m][n] = __builtin_amdgcn_mfma_f32_16x16x32_bf16(af[m], bfr[n], acc[m][n], 0, 0, 0);
        }

        __hip_bfloat16* ta = pa0; pa0 = pa1; pa1 = pa2; pa2 = ta;
        __hip_bfloat16* tb = pb0; pb0 = pb1; pb1 = pb2; pb2 = tb;
    }

    #pragma unroll
    for (int m = 0; m < 2; ++m) {
        #pragma unroll
        for (int n = 0; n < 4; ++n) {
            const int gcol = cn * 128 + wn * 64 + n * 16 + l15;   // 0..767
            const float bcol = bias[gcol];
            const int nh = gcol >> 6, d = gcol & 63;
            const int grow0 = rm * 128 + wm * 32 + m * 16 + lhi * 4;
            const int bb = grow0 >> 10, ll0 = grow0 & 1023;
            if (wsel == 2) {
                bf16x4 pk;
                #pragma unroll
                for (int r = 0; r < 4; ++r)
                    ((__hip_bfloat16*)&pk)[r] = __float2bfloat16(acc[m][n][r] + bcol);
                *(bf16x4*)&v_t[(size_t)((bb * 12 + nh) * 64 + d) * 1024 + ll0] = pk;
            } else {
                #pragma unroll
                for (int r = 0; r < 4; ++r) {
                    const int ll = ll0 + r;
                    const float val = acc[m][n][r] + bcol;
                    const float other = __shfl_xor(val, 1);
                    const float cs = cosp[ll * 64 + d];
                    const float sn = sinp[ll * 64 + d];
                    float res = val * cs + ((d & 1) ? other : -other) * sn;
                    res *= (wsel == 1) ? 0.125f : LOG2E;
                    __hip_bfloat16* dst = (wsel == 1) ? kr : qr;
                    dst[(size_t)((bb * 12 + nh) * 1024 + ll) * 64 + d] = __float2bfloat16(res);
                }
            }
        }
    }
}

// ---------------------------------------------------------------------------
// Kernel 2: FUSED attention + LEPE conv, 512 threads / 8 waves.
// blocks 0..767 : attention, QBLK=128 (8 waves share ONE K/V tile; per-wave
//                 work unchanged -> per-thread staging HALVED, barriers per
//                 q-row halved, occupancy cap 4 blocks x 8 waves = 32/CU).
// blocks 768..1151: depthwise 5x5 conv, 16 channels/block, vectorized.
// ---------------------------------------------------------------------------
union SMem {
    struct {
        __hip_bfloat16 K[64][LDS_PAD];
        __hip_bfloat16 V[64][LDS_PAD];
        __hip_bfloat16 P[8][16][LDS_PAD];
    } a;                                   // 36,864 B
    __hip_bfloat16 img[16][1032];          // 33,024 B (row stride = 4 banks)
};

__global__ __launch_bounds__(512) void attn_lepe(
    const __hip_bfloat16* __restrict__ qr,
    const __hip_bfloat16* __restrict__ kr,
    const __hip_bfloat16* __restrict__ v_t,
    const float* __restrict__ mask,
    const float* __restrict__ lw,
    const float* __restrict__ lb,
    __hip_bfloat16* __restrict__ attn_out,
    __hip_bfloat16* __restrict__ lepeb)
{
    __shared__ __align__(16) SMem smem;

    const int blk = blockIdx.x;
    const int t = threadIdx.x;

    if (blk >= 768) {
        // ----------------- LEPE path (16 channels/block) -----------------
        const int lbk = blk - 768;
        const int b  = lbk / 48;
        const int cg = lbk % 48;
        const int c0 = cg * 16;

        for (int i = t; i < 4096; i += 512) {
            const int ci = i >> 8, l4 = (i & 255) << 2;
            const int c = c0 + ci, nh = c >> 6, d = c & 63;
            *(bf16x4*)&smem.img[ci][l4] =
                *(const bf16x4*)&v_t[(size_t)((b * 12 + nh) * 64 + d) * 1024 + l4];
        }
        __syncthreads();

        const int ci = t & 15, c = c0 + ci;
        const int h  = t >> 4;            // 0..31
        float wt[25];
        #pragma unroll
        for (int k = 0; k < 25; ++k) wt[k] = lw[k * 768 + c];
        const float bias = lb[c];

        #pragma unroll
        for (int wb = 0; wb < 4; ++wb) {
            float acc8[8];
            #pragma unroll
            for (int j = 0; j < 8; ++j) acc8[j] = bias;

            #pragma unroll
            for (int dy = 0; dy < 5; ++dy) {
                const int hy = h + dy - 2;
                if (hy < 0 || hy > 31) continue;
                float v[12];
                #pragma unroll
                for (int cc = 0; cc < 3; ++cc) {
                    const int cch = wb - 1 + cc;
                    if (cch < 0 || cch > 3) continue;
                    const bf16x8 chunk = *(const bf16x8*)&smem.img[ci][hy * 32 + cch * 8];
                    #pragma unroll
                    for (int e = 0; e < 8; ++e) {
                        const int j = cch * 8 + e - (wb * 8 - 2);
                        if (j >= 0 && j < 12)
                            v[j] = bf2f(((const __hip_bfloat16*)&chunk)[e]);
                    }
                }
                #pragma unroll
                for (int j = 0; j < 12; ++j) {
                    const int x = wb * 8 + j - 2;
                    if (x < 0 || x > 31) v[j] = 0.f;
                }
                #pragma unroll
                for (int jw = 0; jw < 8; ++jw)
                    #pragma unroll
                    for (int dx = 0; dx < 5; ++dx)
                        acc8[jw] = fmaf(v[jw + dx], wt[dy * 5 + dx], acc8[jw]);
            }

            #pragma unroll
            for (int jw = 0; jw < 8; ++jw)
                lepeb[(size_t)(b * 1024 + h * 32 + wb * 8 + jw) * 768 + c] =
                    __float2bfloat16(acc8[jw]);
        }
        return;
    }

    // ----------------- attention path (8 waves, QBLK=128) -----------------
    const int qt = blk & 7;         // 0..7
    const int bh = blk >> 3;        // 0..95
    const int b = bh / 12, nh = bh % 12;

    const int lane = t & 63, w = t >> 6;   // w 0..7
    const int l15 = lane & 15, lhi = lane >> 4;
    const int qg = qt * 128 + w * 16 + l15;

    bf16x8 qf[2];   // q pre-scaled by log2(e)
    qf[0] = *(const bf16x8*)&qr[((size_t)bh * 1024 + qg) * 64 + lhi * 8];
    qf[1] = *(const bf16x8*)&qr[((size_t)bh * 1024 + qg) * 64 + 32 + lhi * 8];

    f32x4 o[4] = {};
    float l_run = 0.f;

    const int srow = t >> 3;        // 0..63 (512 threads cover tile in one go)
    const int scol = (t & 7) * 8;

    const float* mbase = mask + ((size_t)nh << 20) + (size_t)qg * 1024;

    bf16x8 kb0, vb0;
    float4 mv[4];
    {
        kb0 = *(const bf16x8*)&kr[((size_t)bh * 1024 + srow) * 64 + scol];
        vb0 = *(const bf16x8*)&v_t[(size_t)(bh * 64 + srow) * 1024 + scol];
        #pragma unroll
        for (int n = 0; n < 4; ++n)
            mv[n] = *(const float4*)&mbase[n * 16 + lhi * 4];
    }

    for (int kt = 0; kt < 16; ++kt) {
        *(bf16x8*)&smem.a.K[srow][scol] = kb0;
        *(bf16x8*)&smem.a.V[srow][scol] = vb0;
        __syncthreads();

        float4 mvn[4];
        if (kt < 15) {
            kb0 = *(const bf16x8*)&kr[((size_t)bh * 1024 + (kt + 1) * 64 + srow) * 64 + scol];
            vb0 = *(const bf16x8*)&v_t[(size_t)(bh * 64 + srow) * 1024 + (kt + 1) * 64 + scol];
            #pragma unroll
            for (int n = 0; n < 4; ++n)
                mvn[n] = *(const float4*)&mbase[(kt + 1) * 64 + n * 16 + lhi * 4];
        }

        f32x4 s[4] = {};
        __builtin_amdgcn_s_setprio(1);
        #pragma unroll
        for (int n = 0; n < 4; ++n) {
            const bf16x8 kf0 = *(const bf16x8*)&smem.a.K[n * 16 + l15][lhi * 8];
            const bf16x8 kf1 = *(const bf16x8*)&smem.a.K[n * 16 + l15][32 + lhi * 8];
            s[n] = __builtin_amdgcn_mfma_f32_16x16x32_bf16(kf0, qf[0], s[n], 0, 0, 0);
            s[n] = __builtin_amdgcn_mfma_f32_16x16x32_bf16(kf1, qf[1], s[n], 0, 0, 0);
        }
        __builtin_amdgcn_s_setprio(0);

        #pragma unroll
        for (int n = 0; n < 4; ++n) {
            bf16x4 pk;
            #pragma unroll
            for (int r = 0; r < 4; ++r) {
                const float p = exp2f(fmaf(((const float*)&mv[n])[r], LOG2E, s[n][r]));
                l_run += p;
                ((__hip_bfloat16*)&pk)[r] = __float2bfloat16(p);
            }
            *(bf16x4*)&smem.a.P[w][l15][n * 16 + lhi * 4] = pk;
        }
        asm volatile("s_waitcnt lgkmcnt(0)" ::: "memory");
        __builtin_amdgcn_sched_barrier(0);

        __builtin_amdgcn_s_setprio(1);
        #pragma unroll
        for (int ks = 0; ks < 2; ++ks) {
            const bf16x8 pf = *(const bf16x8*)&smem.a.P[w][l15][ks * 32 + lhi * 8];
            #pragma unroll
            for (int m = 0; m < 4; ++m) {
                const bf16x8 vf = *(const bf16x8*)&smem.a.V[m * 16 + l15][ks * 32 + lhi * 8];
                o[m] = __builtin_amdgcn_mfma_f32_16x16x32_bf16(vf, pf, o[m], 0, 0, 0);
            }
        }
        __builtin_amdgcn_s_setprio(0);
        __syncthreads();

        #pragma unroll
        for (int n = 0; n < 4; ++n) mv[n] = mvn[n];
    }

    l_run += __shfl_xor(l_run, 16);
    l_run += __shfl_xor(l_run, 32);

    const float rl = 1.f / l_run;
    #pragma unroll
    for (int m = 0; m < 4; ++m) {
        bf16x4 pk;
        #pragma unroll
        for (int r = 0; r < 4; ++r)
            ((__hip_bfloat16*)&pk)[r] = __float2bfloat16(o[m][r] * rl);
        *(bf16x4*)&attn_out[((size_t)b * 1024 + qg) * 768 + nh * 64 + m * 16 + lhi * 4] = pk;
    }
}

// ---------------------------------------------------------------------------
// Kernel 3: output projection: out = (aout + lepeb) @ wo^T + bo.
// 512 threads / 8 waves, wave tile 32x64. A reg-staged with fused add
// (prefetched one K-step ahead); B via gload_lds.
// ---------------------------------------------------------------------------
__global__ __launch_bounds__(512) void proj_gemm(
    const __hip_bfloat16* __restrict__ aout,
    const __hip_bfloat16* __restrict__ lepeb,
    const __hip_bfloat16* __restrict__ wb,
    const float* __restrict__ bo,
    float* __restrict__ out)
{
    __shared__ __align__(16) __hip_bfloat16 Alds[128 * 64];
    __shared__ __align__(16) __hip_bfloat16 Blds[128 * 64];

    const int t    = threadIdx.x;
    const int lane = t & 63;
    const int w    = t >> 6;
    const int wm   = w >> 1, wn = w & 1;
    const int l15  = lane & 15, lhi = lane >> 4;

    const int rm = blockIdx.x, cn = blockIdx.y;
    const __hip_bfloat16* wgt = wb + (size_t)3 * 589824;

    const int srow = w * 16 + (lane >> 3);
    const int scol = (lane & 7) * 8;
    const size_t aoff0 = (size_t)(rm * 128 + srow) * 768 + scol;
    const __hip_bfloat16* bsrc = wgt + (size_t)(cn * 128 + srow) * 768 + scol;
    const int lds_off = srow * 64 + scol;

    f32x4 acc[2][4] = {};

    bf16x8 ar[2];
    #pragma unroll
    for (int j = 0; j < 2; ++j) {
        const size_t off = aoff0 + (size_t)j * 8 * 768;
        const bf16x8 a1 = *(const bf16x8*)&aout[off];
        const bf16x8 a2 = *(const bf16x8*)&lepeb[off];
        #pragma unroll
        for (int e = 0; e < 8; ++e)
            ((__hip_bfloat16*)&ar[j])[e] = __float2bfloat16(
                bf2f(((const __hip_bfloat16*)&a1)[e]) + bf2f(((const __hip_bfloat16*)&a2)[e]));
    }

    for (int k0 = 0; k0 < 768; k0 += 64) {
        __syncthreads();
        #pragma unroll
        for (int j = 0; j < 2; ++j)
            *(bf16x8*)&Alds[lds_off + j * 8 * 64] = ar[j];
        #pragma unroll
        for (int j = 0; j < 2; ++j)
            gload_lds16(bsrc + (size_t)j * 8 * 768 + k0, Blds + (w * 2 + j) * 512);
        __syncthreads();

        if (k0 + 64 < 768) {
            #pragma unroll
            for (int j = 0; j < 2; ++j) {
                const size_t off = aoff0 + (size_t)j * 8 * 768 + k0 + 64;
                const bf16x8 a1 = *(const bf16x8*)&aout[off];
                const bf16x8 a2 = *(const bf16x8*)&lepeb[off];
                #pragma unroll
                for (int e = 0; e < 8; ++e)
                    ((__hip_bfloat16*)&ar[j])[e] = __float2bfloat16(
                        bf2f(((const __hip_bfloat16*)&a1)[e]) + bf2f(((const __hip_bfloat16*)&a2)[e]));
            }
        }

        #pragma unroll
        for (int kk = 0; kk < 2; ++kk) {
            bf16x8 af[2], bfr[4];
            #pragma unroll
            for (int m = 0; m < 2; ++m)
                af[m] = *(const bf16x8*)&Alds[(wm * 32 + m * 16 + l15) * 64 + kk * 32 + lhi * 8];
            #pragma unroll
            for (int n = 0; n < 4; ++n)
                bfr[n] = *(const bf16x8*)&Blds[(wn * 64 + n * 16 + l15) * 64 + kk * 32 + lhi * 8];
            #pragma unroll
            for (int m = 0; m < 2; ++m)
                #pragma unroll
                for (int n = 0; n < 4; ++n)
                    acc[m][n] = __builtin_amdgcn_mfma_f32_16x16x32_bf16(af[m], bfr[n], acc[m][n], 0, 0, 0);
        }
    }

    #pragma unroll
    for (int m = 0; m < 2; ++m)
        #pragma unroll
        for (int n = 0; n < 4; ++n) {
            const int gcol = cn * 128 + wn * 64 + n * 16 + l15;
            const float bcol = bo[gcol];
            #pragma unroll
            for (int r = 0; r < 4; ++r) {
                const int grow = rm * 128 + wm * 32 + m * 16 + lhi * 4 + r;
                out[(size_t)grow * 768 + gcol] = acc[m][n][r] + bcol;
            }
        }
}

// ---------------------------------------------------------------------------
extern "C" void kernel_launch(void* const* d_in, const int* in_sizes, int n_in,
                              void* d_out, int out_size, void* d_ws, size_t ws_size,
                              hipStream_t stream) {
    const float* x    = (const float*)d_in[0];
    const float* sinp = (const float*)d_in[1];
    const float* cosp = (const float*)d_in[2];
    const float* mask = (const float*)d_in[3];
    const float* wq   = (const float*)d_in[4];
    const float* bq   = (const float*)d_in[5];
    const float* wk   = (const float*)d_in[6];
    const float* bk   = (const float*)d_in[7];
    const float* wvw  = (const float*)d_in[8];
    const float* bv   = (const float*)d_in[9];
    const float* lw   = (const float*)d_in[10];
    const float* lb   = (const float*)d_in[11];
    const float* wo   = (const float*)d_in[12];
    const float* bo   = (const float*)d_in[13];
    float* out = (float*)d_out;

    char* ws = (char*)d_ws;
    const size_t SZ = (size_t)8192 * 768 * 2;    // 12.58 MB per bf16 buffer
    __hip_bfloat16* qr    = (__hip_bfloat16*)(ws);
    __hip_bfloat16* kr    = (__hip_bfloat16*)(ws + SZ);
    __hip_bfloat16* v_t   = (__hip_bfloat16*)(ws + 2 * SZ);
    __hip_bfloat16* xb    = (__hip_bfloat16*)(ws + 3 * SZ);
    __hip_bfloat16* wb    = (__hip_bfloat16*)(ws + 4 * SZ);             // 4.5 MB
    __hip_bfloat16* lepeb = (__hip_bfloat16*)(ws + 4 * SZ + 4718592);   // 12.58 MB
    __hip_bfloat16* aout  = xb;   // xb dead after qkv_gemm

    cvt_in<<<dim3(4224), 256, 0, stream>>>(x, wq, wk, wvw, wo, xb, wb);
    qkv_gemm<<<dim3(64, 18), 512, 0, stream>>>(xb, wb, bq, bk, bv,
                                               sinp, cosp, qr, kr, v_t);
    attn_lepe<<<dim3(1152), 512, 0, stream>>>(qr, kr, v_t, mask, lw, lb, aout, lepeb);
    proj_gemm<<<dim3(64, 6), 512, 0, stream>>>(aout, lepeb, wb, bo, out);
}